// Round 9
// baseline (430.042 us; speedup 1.0000x reference)
//
#include <hip/hip_runtime.h>

// ---------------- problem constants ----------------
#define B_     8192
#define D_     32
#define H_     128
#define PH_    64
#define PREP_  10
#define CS_    8
#define CH_    32
#define NT_    16
#define NO_    4096
#define NPOST_ 4
#define DT_    0.1f
#define TWO_LOGC 1.8378770664093453f   // 2*log(sqrt(2*pi))

// ---------------- bf16 fragment-blob offsets (ushort elements) ----------------
// blob layout for a KxN weight: element ((kc*ntiles+nt)*64+lane)*8+j holds
// W[kc*32 + 4*((lane>>4)&3) + (j&3) + 16*(j>>2)][nt*16 + (lane&15)]
// Merged: XZXN = [xz_w | xn_w] (64x256), WIH = w_ih (320x384), WHH = w_hh (128x384).
#define OFF_XZXN 0        // 64x256   -> 16384
#define OFF_HZ   16384    // 128x128  -> 16384
#define OFF_HN   32768    // 128x128  -> 16384
#define OFF_PW1  49152    // 128x64   -> 8192
#define OFF_PW2  57344    // 64x64    -> 4096
#define OFF_WIH  61440    // 320x384  -> 122880
#define OFF_WHH  184320   // 128x384  -> 49152
#define BLOB_ELEMS 233472
#define INV_BYTE_OFF ((size_t)BLOB_ELEMS*2)

// activation LDS strides (ushorts): stride_dw % 32 == 4 -> worst 2-way (free)
#define STRH 136
#define STRP 72
#define STRG 328
#define PFSTR 67          // fp32 p stride (floats)

// shared fp32 constant table offsets (floats)
#define SB_XZ    0
#define SB_XN    128
#define SB_P1    256
#define SB_P2    320
#define SB_BRZ   384      // b_ih+b_hh for r (0..127) and z (128..255)
#define SB_BIN   640      // b_ih n-chunk
#define SB_BHN   768      // b_hh n-chunk
#define SB_WPREP 896      // 1280
#define SB_BPREP 2176     // 320
#define SB_TOT   2496

typedef float f4  __attribute__((ext_vector_type(4)));
typedef short bf8 __attribute__((ext_vector_type(8)));

__device__ __forceinline__ f4 mfma16(bf8 a, bf8 b, f4 c){
  return __builtin_amdgcn_mfma_f32_16x16x32_bf16(a,b,c,0,0,0);
}
__device__ __forceinline__ unsigned short f2bf(float f){
  unsigned int u = __builtin_bit_cast(unsigned int, f);
  u = (u + 0x7FFFu + ((u>>16)&1u)) >> 16;
  return (unsigned short)u;
}
__device__ __forceinline__ float sigmoidf_(float x){ return 1.f/(1.f+__expf(-x)); }
// column k -> ushort position inside a swizzled activation row (fragment order)
__device__ __forceinline__ int permk(int k){
  return ((k>>5)<<5) | (((k>>2)&3)<<3) | (((k>>4)&1)<<2) | (k&3);
}

// Wave-sliced GEMM: rows = NRT*16, wave owns col tiles {tile0 + s*8 : s<NSEL}
// of an NTT-tile-wide fragment blob. A from swizzled LDS (1 ds_read_b128 per
// row-tile per kc), B streamed from L2-resident global blob.
// FULL unroll: at 2 waves/SIMD pinned (waves_per_eu(2,2)) the budget is 256
// regs/wave, so the whole B-load batch can be in flight (deep ILP replaces
// the TLP the register file can't support; R6-R8 lesson).
template<int NKC,int NSEL,int NTT,int NRT>
__device__ __forceinline__ void gemmW(f4 (&acc)[NRT][NSEL], const unsigned short* Ald,
                                      int strideUsh, const unsigned short* __restrict__ Bg,
                                      int lane, int tile0){
  const int lc = lane & 15, a4 = lane >> 4;
  const unsigned short* a0 = Ald + lc*strideUsh + a4*8;
  const unsigned short* bl = Bg + (size_t)tile0*512 + lane*8;
  #pragma unroll
  for(int kc=0;kc<NKC;kc++){
    bf8 av0 = *(const bf8*)(a0 + kc*32);
    bf8 av1;
    if constexpr(NRT==2) av1 = *(const bf8*)(a0 + 16*strideUsh + kc*32);
    #pragma unroll
    for(int s=0;s<NSEL;s++){
      bf8 bv = *(const bf8*)(bl + (size_t)(kc*NTT + s*8)*512);
      acc[0][s] = mfma16(av0, bv, acc[0][s]);
      if constexpr(NRT==2) acc[1][s] = mfma16(av1, bv, acc[1][s]);
    }
  }
}

// ---------------- prep kernels ----------------
__global__ void init_inv(unsigned short* inv, float* outLoss){
  int i = blockIdx.x*256 + threadIdx.x;
  if(i < NT_*B_) inv[i] = 0xFFFFu;
  if(i == 0) *outLoss = 0.f;
}

__global__ void scatter_inv(unsigned short* inv, const int* __restrict__ obs){
  int i = blockIdx.x*256 + threadIdx.x;
  if(i < NT_*NO_){
    int t = i >> 12;
    int o = i & 4095;
    inv[(size_t)t*B_ + obs[i]] = (unsigned short)o;
  }
}

__global__ void build_blobs(const float* __restrict__ pw1, const float* __restrict__ pw2,
                            const float* __restrict__ xzw, const float* __restrict__ xnw,
                            const float* __restrict__ hzw, const float* __restrict__ hnw,
                            const float* __restrict__ wih, const float* __restrict__ whh,
                            unsigned short* __restrict__ blob){
  int sec = blockIdx.y;
  int e = blockIdx.x*256 + threadIdx.x;
  const float* src=nullptr; int N, ld, off, cnt;
  switch(sec){
    case 0: src=nullptr; N=256; ld=0;   off=OFF_XZXN; cnt=16384;  break; // [xz|xn]
    case 1: src=hzw;  N=128; ld=128; off=OFF_HZ;   cnt=16384;  break;
    case 2: src=hnw;  N=128; ld=128; off=OFF_HN;   cnt=16384;  break;
    case 3: src=pw1;  N=64;  ld=64;  off=OFF_PW1;  cnt=8192;   break;
    case 4: src=pw2;  N=64;  ld=64;  off=OFF_PW2;  cnt=4096;   break;
    case 5: src=wih;  N=384; ld=384; off=OFF_WIH;  cnt=122880; break;
    default:src=whh;  N=384; ld=384; off=OFF_WHH;  cnt=49152;  break;
  }
  if(e >= cnt) return;
  int ntiles = N >> 4;
  int perkc = ntiles << 9;
  int kc = e / perkc, rem = e % perkc;
  int nt = rem >> 9, li = rem & 511;
  int lane = li >> 3, j = li & 7;
  int n = nt*16 + (lane & 15);
  int k = kc*32 + ((lane>>4)&3)*4 + (j&3) + ((j>>2)<<4);
  float v;
  if(sec==0) v = (n<128) ? xzw[(size_t)k*128+n] : xnw[(size_t)k*128 + (n-128)];
  else       v = src[(size_t)k*ld + n];
  blob[off + e] = f2bf(v);
}

// ---------------- fused persistent kernel ----------------
// 256 blocks x 512 threads (8 waves = 2 waves/SIMD); 32 rows/block.
// Wave w owns h-col slice [16w,16w+16) of every 128/384-wide GEMM.
// waves_per_eu(2,2): pin occupancy at 2 waves/SIMD -> 256-reg/wave budget.
// (R6-R8: 1024-thread blocks hard-cap at 128 regs/wave -> unavoidable spill.)
__global__ __launch_bounds__(512)
__attribute__((amdgpu_waves_per_eu(2,2))) void fused(
    const float* __restrict__ X, const float* __restrict__ M,
    const float* __restrict__ cov,
    const float* __restrict__ cm_w1, const float* __restrict__ cm_b1,
    const float* __restrict__ cm_w2, const float* __restrict__ cm_b2,
    const float* __restrict__ p_b1, const float* __restrict__ p_b2,
    const float* __restrict__ xz_b, const float* __restrict__ xn_b,
    const float* __restrict__ b_ih, const float* __restrict__ b_hh,
    const float* __restrict__ w_prep, const float* __restrict__ bias_prep,
    const unsigned short* __restrict__ blob, const unsigned short* __restrict__ inv,
    float* __restrict__ outH, float* __restrict__ outP, float* __restrict__ outLoss)
{
  __shared__ __align__(16) unsigned short hb[32*STRH];   // bf16 h (swizzled)
  __shared__ __align__(16) unsigned short pb[32*STRP];   // bf16 p
  __shared__ __align__(16) unsigned short un[32*STRG];   // union: qb / zh / gin
  __shared__ __align__(16) float pf32[32*PFSTR];         // fp32 p
  __shared__ float sb[SB_TOT];
  __shared__ int obsO[32];
  __shared__ float lred[8];

  const int tid  = threadIdx.x;
  const int lane = tid & 63;
  const int w    = tid >> 6;           // wave 0..7
  const int lc   = lane & 15;
  const int a4   = lane >> 4;          // 0..3
  const int base = blockIdx.x * 32;
  float lsum = 0.f;

  // ---- stage fp32 constants ----
  for(int i=tid;i<128;i+=512){ sb[SB_XZ+i]=xz_b[i]; sb[SB_XN+i]=xn_b[i];
                               sb[SB_BIN+i]=b_ih[256+i]; sb[SB_BHN+i]=b_hh[256+i]; }
  for(int i=tid;i<64;i+=512){ sb[SB_P1+i]=p_b1[i]; sb[SB_P2+i]=p_b2[i]; }
  for(int i=tid;i<256;i+=512) sb[SB_BRZ+i]=b_ih[i]+b_hh[i];
  for(int i=tid;i<1280;i+=512) sb[SB_WPREP+i]=w_prep[i];
  for(int i=tid;i<320;i+=512) sb[SB_BPREP+i]=bias_prep[i];

  // ---- init h = tanh(relu(cov@cm_w1+b1)@cm_w2+b2) (one-time scalar path) ----
  {
    float* c1f = pf32;                  // [32][36] scratch
    float* hInitF = (float*)un;         // [32][132] scratch
    int row = tid>>4, q = tid&15;
    float a[2];
    #pragma unroll
    for(int j=0;j<2;j++) a[j]=cm_b1[q*2+j];
    #pragma unroll
    for(int k=0;k<CS_;k++){
      float cv = cov[(size_t)(base+row)*CS_+k];
      #pragma unroll
      for(int j=0;j<2;j++) a[j] += cv*cm_w1[k*CH_+q*2+j];
    }
    #pragma unroll
    for(int j=0;j<2;j++) c1f[row*36+q*2+j] = fmaxf(a[j],0.f);
    __syncthreads();
    float acc2[8];
    #pragma unroll
    for(int j=0;j<8;j++) acc2[j]=cm_b2[q*8+j];
    for(int k=0;k<CH_;k++){
      float cv = c1f[row*36+k];
      #pragma unroll
      for(int j=0;j<8;j++) acc2[j] += cv*cm_w2[k*H_+q*8+j];
    }
    #pragma unroll
    for(int j=0;j<8;j++) hInitF[row*132+q*8+j] = tanhf(acc2[j]);
    __syncthreads();
  }

  f4 hFr[2];        // h cols [16w,16w+16), rows rt*16+a4*4+g
  f4 pFr;           // p rows prt*16+a4*4+g, col pct*16+lc
  const int prt = w & 1, pct = w >> 1;
  {
    float* hInitF = (float*)un;
    #pragma unroll
    for(int rt=0;rt<2;rt++)
      #pragma unroll
      for(int g=0;g<4;g++)
        hFr[rt][g] = hInitF[(rt*16+a4*4+g)*132 + w*16+lc];
    __syncthreads();                    // reads done before un reuse / hb write
    #pragma unroll
    for(int rt=0;rt<2;rt++)
      #pragma unroll
      for(int g=0;g<4;g++)
        hb[(rt*16+a4*4+g)*STRH + permk(w*16+lc)] = f2bf(hFr[rt][g]);
    __syncthreads();
  }

  // ---- p_model: wave w -> rows [16*prt), cols [16*pct) ----
  auto pmodel = [&](){
    f4 acc[1][1];
    { float bv = sb[SB_P1 + pct*16+lc]; f4 t={bv,bv,bv,bv}; acc[0][0]=t; }
    gemmW<4,1,4,1>(acc, hb + prt*16*STRH, STRH, blob+OFF_PW1, lane, pct);
    #pragma unroll
    for(int g=0;g<4;g++)
      un[(prt*16+a4*4+g)*STRP + permk(pct*16+lc)] = f2bf(fmaxf(acc[0][0][g],0.f));
    __syncthreads();
    { float bv = sb[SB_P2 + pct*16+lc]; f4 t={bv,bv,bv,bv}; acc[0][0]=t; }
    gemmW<2,1,4,1>(acc, un + prt*16*STRP, STRP, blob+OFF_PW2, lane, pct);
    pFr = acc[0][0];
    #pragma unroll
    for(int g=0;g<4;g++){
      int row = prt*16+a4*4+g, col = pct*16+lc;
      float v = acc[0][0][g];
      pb[row*STRP + permk(col)] = f2bf(v);
      pf32[row*PFSTR + col] = v;
    }
    __syncthreads();
  };

  // ---- euler: h += DT*(1-z)*(n-h); wave w owns h cols [16w,16w+16) ----
  auto euler = [&](){
    f4 ax[2][2];   // [rt][0]=xz part, [rt][1]=xn part (merged 256-wide blob)
    #pragma unroll
    for(int rt=0;rt<2;rt++){
      float bz = sb[SB_XZ + w*16+lc], bn = sb[SB_XN + w*16+lc];
      f4 tz={bz,bz,bz,bz}, tn={bn,bn,bn,bn};
      ax[rt][0]=tz; ax[rt][1]=tn;
    }
    gemmW<2,2,16,2>(ax, pb, STRP, blob+OFF_XZXN, lane, w);
    f4 ah[2][1]; { f4 z4={0.f,0.f,0.f,0.f}; ah[0][0]=z4; ah[1][0]=z4; }
    gemmW<4,1,8,2>(ah, hb, STRH, blob+OFF_HZ, lane, w);
    f4 zr[2];
    #pragma unroll
    for(int rt=0;rt<2;rt++)
      #pragma unroll
      for(int g=0;g<4;g++){
        float z = sigmoidf_(ax[rt][0][g] + ah[rt][0][g]);
        zr[rt][g]=z;
        un[(rt*16+a4*4+g)*STRH + permk(w*16+lc)] = f2bf(z*hFr[rt][g]);   // zh
      }
    __syncthreads();
    { f4 z4={0.f,0.f,0.f,0.f}; ah[0][0]=z4; ah[1][0]=z4; }
    gemmW<4,1,8,2>(ah, un, STRH, blob+OFF_HN, lane, w);
    #pragma unroll
    for(int rt=0;rt<2;rt++)
      #pragma unroll
      for(int g=0;g<4;g++){
        float nn = tanhf(ax[rt][1][g] + ah[rt][0][g]);
        float ho = hFr[rt][g];
        float hv = ho + DT_*(1.f-zr[rt][g])*(nn-ho);
        hFr[rt][g]=hv;
        hb[(rt*16+a4*4+g)*STRH + permk(w*16+lc)] = f2bf(hv);
      }
    __syncthreads();
  };

  // ---- Bayesian jump: merged-gate GEMMs (tiles {w, w+8, w+16} of 384-wide) ----
  auto jump = [&](int t){
    if(tid < 32){
      unsigned short v = inv[(size_t)t*B_ + base + tid];
      obsO[tid] = (v == 0xFFFFu) ? -1 : (int)v;
    }
    __syncthreads();
    { // gin + loss: thread -> (row = tid>>4, d in {2q,2q+1})
      int row = tid>>4, q = tid&15, d0 = q*2;
      int o = obsO[row];
      float xa[2]={0.f,0.f}, ma[2]={0.f,0.f};
      if(o>=0){
        const float2 xv = *(const float2*)(X + ((size_t)t*NO_+o)*D_ + d0);
        const float2 mv = *(const float2*)(M + ((size_t)t*NO_+o)*D_ + d0);
        xa[0]=xv.x; xa[1]=xv.y; ma[0]=mv.x; ma[1]=mv.y;
      }
      #pragma unroll
      for(int j=0;j<2;j++){
        int d = d0+j;
        float mean = pf32[row*PFSTR + d];
        float lv   = pf32[row*PFSTR + D_ + d];
        float sg = __expf(0.5f*lv);
        float er = (xa[j]-mean)/sg;
        if(ma[j]>0.f) lsum += 0.5f*(er*er + lv + TWO_LOGC);
        const float* wp  = sb + SB_WPREP + d*4*PREP_;
        const float* bpv = sb + SB_BPREP + d*PREP_;
        #pragma unroll
        for(int pr=0;pr<PREP_;pr++){
          float s = xa[j]*wp[pr] + mean*wp[PREP_+pr] + lv*wp[2*PREP_+pr] + er*wp[3*PREP_+pr] + bpv[pr];
          s = fmaxf(s,0.f);
          un[row*STRG + permk(d*PREP_+pr)] = f2bf((ma[j]>0.f)? s : 0.f);  // gin
        }
      }
    }
    __syncthreads();
    // gi = gin @ [wih_r|wih_z|wih_n] (+ biases); gh = h @ [whh_r|whh_z|whh_n]
    f4 gi[2][3];
    #pragma unroll
    for(int rt=0;rt<2;rt++){
      float br = sb[SB_BRZ + w*16+lc], bz = sb[SB_BRZ+128 + w*16+lc], bn = sb[SB_BIN + w*16+lc];
      f4 tr={br,br,br,br}, tz={bz,bz,bz,bz}, tn={bn,bn,bn,bn};
      gi[rt][0]=tr; gi[rt][1]=tz; gi[rt][2]=tn;
    }
    gemmW<10,3,24,2>(gi, un, STRG, blob+OFF_WIH, lane, w);
    f4 gh[2][3];
    #pragma unroll
    for(int rt=0;rt<2;rt++){
      float bhn = sb[SB_BHN + w*16+lc];
      f4 z4={0.f,0.f,0.f,0.f}, tn={bhn,bhn,bhn,bhn};
      gh[rt][0]=z4; gh[rt][1]=z4; gh[rt][2]=tn;
    }
    gemmW<4,3,24,2>(gh, hb, STRH, blob+OFF_WHH, lane, w);
    __syncthreads();   // all waves done reading hb/un before conditional hb writes
    #pragma unroll
    for(int rt=0;rt<2;rt++)
      #pragma unroll
      for(int g=0;g<4;g++){
        int row = rt*16+a4*4+g;
        float r = sigmoidf_(gi[rt][0][g] + gh[rt][0][g]);
        float z = sigmoidf_(gi[rt][1][g] + gh[rt][1][g]);
        float nn = tanhf(gi[rt][2][g] + r*gh[rt][2][g]);
        float hv = (1.f-z)*nn + z*hFr[rt][g];
        if(obsO[row]>=0){
          hFr[rt][g]=hv;
          hb[row*STRH + permk(w*16+lc)] = f2bf(hv);
        }
      }
    __syncthreads();
  };

  // ---- sequence ----
  pmodel();
  for(int t=0;t<NT_;t++){
    euler();
    pmodel();
    jump(t);
    pmodel();
  }
  for(int it=0;it<NPOST_;it++){
    euler();
    pmodel();
  }

  // ---- outputs ----
  #pragma unroll
  for(int rt=0;rt<2;rt++)
    #pragma unroll
    for(int g=0;g<4;g++)
      outH[(size_t)(base + rt*16+a4*4+g)*H_ + w*16+lc] = hFr[rt][g];
  #pragma unroll
  for(int g=0;g<4;g++)
    outP[(size_t)(base + prt*16+a4*4+g)*(2*D_) + pct*16+lc] = pFr[g];

  #pragma unroll
  for(int off=32;off>0;off>>=1) lsum += __shfl_down(lsum, off);
  if(lane==0) lred[w]=lsum;
  __syncthreads();
  if(tid==0){
    float s = 0.f;
    #pragma unroll
    for(int i=0;i<8;i++) s += lred[i];
    atomicAdd(outLoss, s);
  }
}

// ---------------- launcher ----------------
extern "C" void kernel_launch(void* const* d_in, const int* in_sizes, int n_in,
                              void* d_out, int out_size, void* d_ws, size_t ws_size,
                              hipStream_t stream){
  const float* X      = (const float*)d_in[0];
  const float* M      = (const float*)d_in[1];
  const int*   obs    = (const int*)  d_in[2];
  const float* cov    = (const float*)d_in[3];
  const float* cm_w1  = (const float*)d_in[4];
  const float* cm_b1  = (const float*)d_in[5];
  const float* cm_w2  = (const float*)d_in[6];
  const float* cm_b2  = (const float*)d_in[7];
  const float* p_w1   = (const float*)d_in[8];
  const float* p_b1   = (const float*)d_in[9];
  const float* p_w2   = (const float*)d_in[10];
  const float* p_b2   = (const float*)d_in[11];
  const float* xz_w   = (const float*)d_in[12];
  const float* xz_b   = (const float*)d_in[13];
  const float* hz_w   = (const float*)d_in[14];
  const float* xn_w   = (const float*)d_in[15];
  const float* xn_b   = (const float*)d_in[16];
  const float* hn_w   = (const float*)d_in[17];
  const float* w_ih   = (const float*)d_in[18];
  const float* w_hh   = (const float*)d_in[19];
  const float* b_ih   = (const float*)d_in[20];
  const float* b_hh   = (const float*)d_in[21];
  const float* w_prep = (const float*)d_in[22];
  const float* bprep  = (const float*)d_in[23];

  unsigned short* blob = (unsigned short*)d_ws;
  unsigned short* inv  = (unsigned short*)((char*)d_ws + INV_BYTE_OFF);
  float* outH = (float*)d_out;
  float* outP = outH + (size_t)B_*H_;
  float* outLoss = outP + (size_t)B_*2*D_;

  init_inv   <<<dim3((NT_*B_+255)/256), dim3(256), 0, stream>>>(inv, outLoss);
  scatter_inv<<<dim3((NT_*NO_+255)/256), dim3(256), 0, stream>>>(inv, obs);
  build_blobs<<<dim3(480,7), dim3(256), 0, stream>>>(p_w1,p_w2,xz_w,xn_w,hz_w,hn_w,w_ih,w_hh, blob);
  fused      <<<dim3(B_/32), dim3(512), 0, stream>>>(
      X, M, cov, cm_w1, cm_b1, cm_w2, cm_b2, p_b1, p_b2, xz_b, xn_b,
      b_ih, b_hh, w_prep, bprep, blob, inv, outH, outP, outLoss);
}

// Round 10
// 256.359 us; speedup vs baseline: 1.6775x; 1.6775x over previous
//
#include <hip/hip_runtime.h>

// ---------------- problem constants ----------------
#define B_     8192
#define D_     32
#define H_     128
#define PH_    64
#define PREP_  10
#define CS_    8
#define CH_    32
#define NT_    16
#define NO_    4096
#define NPOST_ 4
#define DT_    0.1f
#define TWO_LOGC 1.8378770664093453f   // 2*log(sqrt(2*pi))

// ---------------- bf16 fragment-blob offsets (ushort elements) ----------------
// blob layout for a KxN weight: element ((kc*ntiles+nt)*64+lane)*8+j holds
// W[kc*32 + 4*((lane>>4)&3) + (j&3) + 16*(j>>2)][nt*16 + (lane&15)]
// Merged: XZXN = [xz_w | xn_w] (64x256), WIH = w_ih (320x384), WHH = w_hh (128x384).
#define OFF_XZXN 0        // 64x256   -> 16384
#define OFF_HZ   16384    // 128x128  -> 16384
#define OFF_HN   32768    // 128x128  -> 16384
#define OFF_PW1  49152    // 128x64   -> 8192
#define OFF_PW2  57344    // 64x64    -> 4096
#define OFF_WIH  61440    // 320x384  -> 122880
#define OFF_WHH  184320   // 128x384  -> 49152
#define BLOB_ELEMS 233472
#define INV_BYTE_OFF ((size_t)BLOB_ELEMS*2)

// activation LDS strides (ushorts): stride_dw % 32 == 4 -> worst 2-way (free)
#define STRH 136
#define STRP 72
#define STRG 328
#define PFSTR 67          // fp32 p stride (floats)

// shared fp32 constant table offsets (floats)
#define SB_XZ    0
#define SB_XN    128
#define SB_P1    256
#define SB_P2    320
#define SB_BRZ   384      // b_ih+b_hh for r (0..127) and z (128..255)
#define SB_BIN   640      // b_ih n-chunk
#define SB_BHN   768      // b_hh n-chunk
#define SB_WPREP 896      // 1280
#define SB_BPREP 2176     // 320
#define SB_TOT   2496

typedef float f4  __attribute__((ext_vector_type(4)));
typedef short bf8 __attribute__((ext_vector_type(8)));

__device__ __forceinline__ f4 mfma16(bf8 a, bf8 b, f4 c){
  return __builtin_amdgcn_mfma_f32_16x16x32_bf16(a,b,c,0,0,0);
}
__device__ __forceinline__ unsigned short f2bf(float f){
  unsigned int u = __builtin_bit_cast(unsigned int, f);
  u = (u + 0x7FFFu + ((u>>16)&1u)) >> 16;
  return (unsigned short)u;
}
__device__ __forceinline__ float sigmoidf_(float x){ return 1.f/(1.f+__expf(-x)); }
// column k -> ushort position inside a swizzled activation row (fragment order)
__device__ __forceinline__ int permk(int k){
  return ((k>>5)<<5) | (((k>>2)&3)<<3) | (((k>>4)&1)<<2) | (k&3);
}

// 16-row GEMM slice: wave owns col tiles {tile0 + (s>>1)*8 + (s&1) : s<NSEL}
// (i.e. per gate/group of 8 tiles, the pair tile0,tile0+1). A from swizzled
// LDS (1 ds_read_b128 per kc), B streamed from L2-resident global blob.
// unroll 2 caps the in-flight load window (anti-spill; R2/R3/R9 lesson).
template<int NKC,int NSEL,int NTT>
__device__ __forceinline__ void gemmU2(f4 (&acc)[NSEL], const unsigned short* Ald,
                                       int strideUsh, const unsigned short* __restrict__ Bg,
                                       int lane, int tile0){
  const int lc = lane & 15, a4 = lane >> 4;
  const unsigned short* a0 = Ald + lc*strideUsh + a4*8;
  const unsigned short* bl = Bg + (size_t)tile0*512 + lane*8;
  #pragma unroll 2
  for(int kc=0;kc<NKC;kc++){
    bf8 av = *(const bf8*)(a0 + kc*32);
    #pragma unroll
    for(int s=0;s<NSEL;s++){
      bf8 bv = *(const bf8*)(bl + (size_t)(kc*NTT + (s>>1)*8 + (s&1))*512);
      acc[s] = mfma16(av, bv, acc[s]);
    }
  }
}
// unroll-1 variant for the liveness-peak GEMM (gh while gi is still held)
template<int NKC,int NSEL,int NTT>
__device__ __forceinline__ void gemmU1(f4 (&acc)[NSEL], const unsigned short* Ald,
                                       int strideUsh, const unsigned short* __restrict__ Bg,
                                       int lane, int tile0){
  const int lc = lane & 15, a4 = lane >> 4;
  const unsigned short* a0 = Ald + lc*strideUsh + a4*8;
  const unsigned short* bl = Bg + (size_t)tile0*512 + lane*8;
  #pragma unroll 1
  for(int kc=0;kc<NKC;kc++){
    bf8 av = *(const bf8*)(a0 + kc*32);
    #pragma unroll
    for(int s=0;s<NSEL;s++){
      bf8 bv = *(const bf8*)(bl + (size_t)(kc*NTT + (s>>1)*8 + (s&1))*512);
      acc[s] = mfma16(av, bv, acc[s]);
    }
  }
}

// ---------------- prep kernels ----------------
__global__ void init_inv(unsigned short* inv, float* outLoss){
  int i = blockIdx.x*256 + threadIdx.x;
  if(i < NT_*B_) inv[i] = 0xFFFFu;
  if(i == 0) *outLoss = 0.f;
}

__global__ void scatter_inv(unsigned short* inv, const int* __restrict__ obs){
  int i = blockIdx.x*256 + threadIdx.x;
  if(i < NT_*NO_){
    int t = i >> 12;
    int o = i & 4095;
    inv[(size_t)t*B_ + obs[i]] = (unsigned short)o;
  }
}

__global__ void build_blobs(const float* __restrict__ pw1, const float* __restrict__ pw2,
                            const float* __restrict__ xzw, const float* __restrict__ xnw,
                            const float* __restrict__ hzw, const float* __restrict__ hnw,
                            const float* __restrict__ wih, const float* __restrict__ whh,
                            unsigned short* __restrict__ blob){
  int sec = blockIdx.y;
  int e = blockIdx.x*256 + threadIdx.x;
  const float* src=nullptr; int N, ld, off, cnt;
  switch(sec){
    case 0: src=nullptr; N=256; ld=0;   off=OFF_XZXN; cnt=16384;  break; // [xz|xn]
    case 1: src=hzw;  N=128; ld=128; off=OFF_HZ;   cnt=16384;  break;
    case 2: src=hnw;  N=128; ld=128; off=OFF_HN;   cnt=16384;  break;
    case 3: src=pw1;  N=64;  ld=64;  off=OFF_PW1;  cnt=8192;   break;
    case 4: src=pw2;  N=64;  ld=64;  off=OFF_PW2;  cnt=4096;   break;
    case 5: src=wih;  N=384; ld=384; off=OFF_WIH;  cnt=122880; break;
    default:src=whh;  N=384; ld=384; off=OFF_WHH;  cnt=49152;  break;
  }
  if(e >= cnt) return;
  int ntiles = N >> 4;
  int perkc = ntiles << 9;
  int kc = e / perkc, rem = e % perkc;
  int nt = rem >> 9, li = rem & 511;
  int lane = li >> 3, j = li & 7;
  int n = nt*16 + (lane & 15);
  int k = kc*32 + ((lane>>4)&3)*4 + (j&3) + ((j>>2)<<4);
  float v;
  if(sec==0) v = (n<128) ? xzw[(size_t)k*128+n] : xnw[(size_t)k*128 + (n-128)];
  else       v = src[(size_t)k*ld + n];
  blob[off + e] = f2bf(v);
}

// ---------------- fused persistent kernel ----------------
// 512 blocks x 256 threads (4 waves); 16 rows/block -> 2 INDEPENDENT blocks
// per CU. Co-resident blocks interleave phases freely (R5's same-block waves
// were barrier-locked; this buys cross-phase latency overlap without needing
// the >128-VGPR budget the allocator refuses to give).
// Wave w owns col slice [32w,32w+32) of every 128/256/384-wide GEMM.
__global__ __launch_bounds__(256,2) void fused(
    const float* __restrict__ X, const float* __restrict__ M,
    const float* __restrict__ cov,
    const float* __restrict__ cm_w1, const float* __restrict__ cm_b1,
    const float* __restrict__ cm_w2, const float* __restrict__ cm_b2,
    const float* __restrict__ p_b1, const float* __restrict__ p_b2,
    const float* __restrict__ xz_b, const float* __restrict__ xn_b,
    const float* __restrict__ b_ih, const float* __restrict__ b_hh,
    const float* __restrict__ w_prep, const float* __restrict__ bias_prep,
    const unsigned short* __restrict__ blob, const unsigned short* __restrict__ inv,
    float* __restrict__ outH, float* __restrict__ outP, float* __restrict__ outLoss)
{
  __shared__ __align__(16) unsigned short hb[16*STRH];   // bf16 h (swizzled)
  __shared__ __align__(16) unsigned short pb[16*STRP];   // bf16 p
  __shared__ __align__(16) unsigned short un[16*STRG];   // union: qb / zh / gin
  __shared__ __align__(16) float pf32[16*PFSTR];         // fp32 p
  __shared__ float sb[SB_TOT];
  __shared__ int obsO[16];
  __shared__ float lred[4];

  const int tid  = threadIdx.x;
  const int lane = tid & 63;
  const int w    = tid >> 6;           // wave 0..3
  const int lc   = lane & 15;
  const int a4   = lane >> 4;          // 0..3
  const int base = blockIdx.x * 16;
  float lsum = 0.f;

  // ---- stage fp32 constants ----
  for(int i=tid;i<128;i+=256){ sb[SB_XZ+i]=xz_b[i]; sb[SB_XN+i]=xn_b[i];
                               sb[SB_BIN+i]=b_ih[256+i]; sb[SB_BHN+i]=b_hh[256+i]; }
  for(int i=tid;i<64;i+=256){ sb[SB_P1+i]=p_b1[i]; sb[SB_P2+i]=p_b2[i]; }
  for(int i=tid;i<256;i+=256) sb[SB_BRZ+i]=b_ih[i]+b_hh[i];
  for(int i=tid;i<1280;i+=256) sb[SB_WPREP+i]=w_prep[i];
  for(int i=tid;i<320;i+=256) sb[SB_BPREP+i]=bias_prep[i];

  // ---- init h = tanh(relu(cov@cm_w1+b1)@cm_w2+b2) (one-time scalar path) ----
  {
    float* c1f = pf32;                  // [16][36] scratch
    float* hInitF = (float*)un;         // [16][132] scratch
    int row = tid>>4, q = tid&15;       // 16 rows x 16 threads
    float a[2];
    #pragma unroll
    for(int j=0;j<2;j++) a[j]=cm_b1[q*2+j];
    #pragma unroll
    for(int k=0;k<CS_;k++){
      float cv = cov[(size_t)(base+row)*CS_+k];
      #pragma unroll
      for(int j=0;j<2;j++) a[j] += cv*cm_w1[k*CH_+q*2+j];
    }
    #pragma unroll
    for(int j=0;j<2;j++) c1f[row*36+q*2+j] = fmaxf(a[j],0.f);
    __syncthreads();
    float acc2[8];
    #pragma unroll
    for(int j=0;j<8;j++) acc2[j]=cm_b2[q*8+j];
    for(int k=0;k<CH_;k++){
      float cv = c1f[row*36+k];
      #pragma unroll
      for(int j=0;j<8;j++) acc2[j] += cv*cm_w2[k*H_+q*8+j];
    }
    #pragma unroll
    for(int j=0;j<8;j++) hInitF[row*132+q*8+j] = tanhf(acc2[j]);
    __syncthreads();
  }

  f4 hFr[2];        // h rows a4*4+g, cols 32w+16s+lc (s=0,1)
  f4 pFr;           // p rows a4*4+g, col w*16+lc
  {
    float* hInitF = (float*)un;
    #pragma unroll
    for(int s=0;s<2;s++)
      #pragma unroll
      for(int g=0;g<4;g++)
        hFr[s][g] = hInitF[(a4*4+g)*132 + 32*w+16*s+lc];
    __syncthreads();                    // reads done before un reuse / hb write
    #pragma unroll
    for(int s=0;s<2;s++)
      #pragma unroll
      for(int g=0;g<4;g++)
        hb[(a4*4+g)*STRH + permk(32*w+16*s+lc)] = f2bf(hFr[s][g]);
    __syncthreads();
  }

  // ---- p_model: wave w owns cols [16w,16w+16) of q and p ----
  auto pmodel = [&](){
    f4 acc[1];
    { float bv = sb[SB_P1 + w*16+lc]; f4 t={bv,bv,bv,bv}; acc[0]=t; }
    gemmU2<4,1,4>(acc, hb, STRH, blob+OFF_PW1, lane, w);
    #pragma unroll
    for(int g=0;g<4;g++)
      un[(a4*4+g)*STRP + permk(w*16+lc)] = f2bf(fmaxf(acc[0][g],0.f));
    __syncthreads();
    { float bv = sb[SB_P2 + w*16+lc]; f4 t={bv,bv,bv,bv}; acc[0]=t; }
    gemmU2<2,1,4>(acc, un, STRP, blob+OFF_PW2, lane, w);
    pFr = acc[0];
    #pragma unroll
    for(int g=0;g<4;g++){
      int row = a4*4+g, col = w*16+lc;
      float v = acc[0][g];
      pb[row*STRP + permk(col)] = f2bf(v);
      pf32[row*PFSTR + col] = v;
    }
    __syncthreads();
  };

  // ---- euler: h += DT*(1-z)*(n-h); wave w owns h cols [32w,32w+32) ----
  auto euler = [&](){
    f4 ax[4];   // s=0,1: xz cols 32w+16s; s=2,3: xn cols 32w+16(s-2)
    #pragma unroll
    for(int s=0;s<2;s++){
      float bz = sb[SB_XZ + 32*w+16*s+lc], bn = sb[SB_XN + 32*w+16*s+lc];
      f4 tz={bz,bz,bz,bz}, tn={bn,bn,bn,bn};
      ax[s]=tz; ax[2+s]=tn;
    }
    gemmU2<2,4,16>(ax, pb, STRP, blob+OFF_XZXN, lane, 2*w);
    f4 ah[2]; { f4 z4={0.f,0.f,0.f,0.f}; ah[0]=z4; ah[1]=z4; }
    gemmU2<4,2,8>(ah, hb, STRH, blob+OFF_HZ, lane, 2*w);
    f4 zr[2];
    #pragma unroll
    for(int s=0;s<2;s++)
      #pragma unroll
      for(int g=0;g<4;g++){
        float z = sigmoidf_(ax[s][g] + ah[s][g]);
        zr[s][g]=z;
        un[(a4*4+g)*STRH + permk(32*w+16*s+lc)] = f2bf(z*hFr[s][g]);   // zh
      }
    __syncthreads();
    { f4 z4={0.f,0.f,0.f,0.f}; ah[0]=z4; ah[1]=z4; }
    gemmU2<4,2,8>(ah, un, STRH, blob+OFF_HN, lane, 2*w);
    #pragma unroll
    for(int s=0;s<2;s++)
      #pragma unroll
      for(int g=0;g<4;g++){
        float nn = tanhf(ax[2+s][g] + ah[s][g]);
        float ho = hFr[s][g];
        float hv = ho + DT_*(1.f-zr[s][g])*(nn-ho);
        hFr[s][g]=hv;
        hb[(a4*4+g)*STRH + permk(32*w+16*s+lc)] = f2bf(hv);
      }
    __syncthreads();
  };

  // ---- Bayesian jump: merged-gate GEMMs; wave w tiles {2w,2w+1} per gate ----
  auto jump = [&](int t){
    { // gin + loss + obsO publication: thread -> (row=tid>>4, d in {2q,2q+1})
      int row = tid>>4, q = tid&15, d0 = q*2;
      unsigned short v = inv[(size_t)t*B_ + base + row];
      int o = (v==0xFFFFu)? -1 : (int)v;
      if(q==0) obsO[row] = o;
      float xa[2]={0.f,0.f}, ma[2]={0.f,0.f};
      if(o>=0){
        const float2 xv = *(const float2*)(X + ((size_t)t*NO_+o)*D_ + d0);
        const float2 mv = *(const float2*)(M + ((size_t)t*NO_+o)*D_ + d0);
        xa[0]=xv.x; xa[1]=xv.y; ma[0]=mv.x; ma[1]=mv.y;
      }
      #pragma unroll
      for(int j=0;j<2;j++){
        int d = d0+j;
        float mean = pf32[row*PFSTR + d];
        float lv   = pf32[row*PFSTR + D_ + d];
        float sg = __expf(0.5f*lv);
        float er = (xa[j]-mean)/sg;
        if(ma[j]>0.f) lsum += 0.5f*(er*er + lv + TWO_LOGC);
        const float* wp  = sb + SB_WPREP + d*4*PREP_;
        const float* bpv = sb + SB_BPREP + d*PREP_;
        #pragma unroll
        for(int pr=0;pr<PREP_;pr++){
          float s = xa[j]*wp[pr] + mean*wp[PREP_+pr] + lv*wp[2*PREP_+pr] + er*wp[3*PREP_+pr] + bpv[pr];
          s = fmaxf(s,0.f);
          un[row*STRG + permk(d*PREP_+pr)] = f2bf((ma[j]>0.f)? s : 0.f);  // gin
        }
      }
    }
    __syncthreads();
    // gi = gin @ [wih_r|wih_z|wih_n] (+biases); gh = h @ [whh_r|whh_z|whh_n]
    // slot s: gate s>>1 in {r,z,n}... wait: NSEL=6 maps s>>1 to gate, s&1 to col half.
    f4 gi[6];
    #pragma unroll
    for(int s=0;s<2;s++){
      int col = 32*w+16*s+lc;
      float br = sb[SB_BRZ + col], bz = sb[SB_BRZ+128 + col], bn = sb[SB_BIN + col];
      f4 tr={br,br,br,br}, tz={bz,bz,bz,bz}, tn={bn,bn,bn,bn};
      gi[s]=tr; gi[2+s]=tz; gi[4+s]=tn;
    }
    gemmU2<10,6,24>(gi, un, STRG, blob+OFF_WIH, lane, 2*w);
    f4 gh[6];
    #pragma unroll
    for(int s=0;s<2;s++){
      float bhn = sb[SB_BHN + 32*w+16*s+lc];
      f4 z4={0.f,0.f,0.f,0.f}, tn={bhn,bhn,bhn,bhn};
      gh[s]=z4; gh[2+s]=z4; gh[4+s]=tn;
    }
    gemmU1<4,6,24>(gh, hb, STRH, blob+OFF_WHH, lane, 2*w);
    __syncthreads();   // all waves done reading hb/un before conditional hb writes
    #pragma unroll
    for(int s=0;s<2;s++)
      #pragma unroll
      for(int g=0;g<4;g++){
        int row = a4*4+g;
        float r = sigmoidf_(gi[s][g] + gh[s][g]);
        float z = sigmoidf_(gi[2+s][g] + gh[2+s][g]);
        float nn = tanhf(gi[4+s][g] + r*gh[4+s][g]);
        float hv = (1.f-z)*nn + z*hFr[s][g];
        if(obsO[row]>=0){
          hFr[s][g]=hv;
          hb[row*STRH + permk(32*w+16*s+lc)] = f2bf(hv);
        }
      }
    __syncthreads();
  };

  // ---- sequence ----
  pmodel();
  for(int t=0;t<NT_;t++){
    euler();
    pmodel();
    jump(t);
    pmodel();
  }
  for(int it=0;it<NPOST_;it++){
    euler();
    pmodel();
  }

  // ---- outputs ----
  #pragma unroll
  for(int s=0;s<2;s++)
    #pragma unroll
    for(int g=0;g<4;g++)
      outH[(size_t)(base + a4*4+g)*H_ + 32*w+16*s+lc] = hFr[s][g];
  #pragma unroll
  for(int g=0;g<4;g++)
    outP[(size_t)(base + a4*4+g)*(2*D_) + w*16+lc] = pFr[g];

  #pragma unroll
  for(int off=32;off>0;off>>=1) lsum += __shfl_down(lsum, off);
  if(lane==0) lred[w]=lsum;
  __syncthreads();
  if(tid==0) atomicAdd(outLoss, lred[0]+lred[1]+lred[2]+lred[3]);
}

// ---------------- launcher ----------------
extern "C" void kernel_launch(void* const* d_in, const int* in_sizes, int n_in,
                              void* d_out, int out_size, void* d_ws, size_t ws_size,
                              hipStream_t stream){
  const float* X      = (const float*)d_in[0];
  const float* M      = (const float*)d_in[1];
  const int*   obs    = (const int*)  d_in[2];
  const float* cov    = (const float*)d_in[3];
  const float* cm_w1  = (const float*)d_in[4];
  const float* cm_b1  = (const float*)d_in[5];
  const float* cm_w2  = (const float*)d_in[6];
  const float* cm_b2  = (const float*)d_in[7];
  const float* p_w1   = (const float*)d_in[8];
  const float* p_b1   = (const float*)d_in[9];
  const float* p_w2   = (const float*)d_in[10];
  const float* p_b2   = (const float*)d_in[11];
  const float* xz_w   = (const float*)d_in[12];
  const float* xz_b   = (const float*)d_in[13];
  const float* hz_w   = (const float*)d_in[14];
  const float* xn_w   = (const float*)d_in[15];
  const float* xn_b   = (const float*)d_in[16];
  const float* hn_w   = (const float*)d_in[17];
  const float* w_ih   = (const float*)d_in[18];
  const float* w_hh   = (const float*)d_in[19];
  const float* b_ih   = (const float*)d_in[20];
  const float* b_hh   = (const float*)d_in[21];
  const float* w_prep = (const float*)d_in[22];
  const float* bprep  = (const float*)d_in[23];

  unsigned short* blob = (unsigned short*)d_ws;
  unsigned short* inv  = (unsigned short*)((char*)d_ws + INV_BYTE_OFF);
  float* outH = (float*)d_out;
  float* outP = outH + (size_t)B_*H_;
  float* outLoss = outP + (size_t)B_*2*D_;

  init_inv   <<<dim3((NT_*B_+255)/256), dim3(256), 0, stream>>>(inv, outLoss);
  scatter_inv<<<dim3((NT_*NO_+255)/256), dim3(256), 0, stream>>>(inv, obs);
  build_blobs<<<dim3(480,7), dim3(256), 0, stream>>>(p_w1,p_w2,xz_w,xn_w,hz_w,hn_w,w_ih,w_hh, blob);
  fused      <<<dim3(B_/16), dim3(256), 0, stream>>>(
      X, M, cov, cm_w1, cm_b1, cm_w2, cm_b2, p_b1, p_b2, xz_b, xn_b,
      b_ih, b_hh, w_prep, bprep, blob, inv, outH, outP, outLoss);
}

// Round 11
// 226.760 us; speedup vs baseline: 1.8965x; 1.1305x over previous
//
#include <hip/hip_runtime.h>

// ---------------- problem constants ----------------
#define B_     8192
#define D_     32
#define H_     128
#define PH_    64
#define PREP_  10
#define CS_    8
#define CH_    32
#define NT_    16
#define NO_    4096
#define NPOST_ 4
#define DT_    0.1f
#define TWO_LOGC 1.8378770664093453f   // 2*log(sqrt(2*pi))

// ---------------- bf16 fragment-blob offsets (ushort elements) ----------------
// blob layout for a KxN weight: element ((kc*ntiles+nt)*64+lane)*8+j holds
// W[kc*32 + 4*((lane>>4)&3) + (j&3) + 16*(j>>2)][nt*16 + (lane&15)]
// Merged: XZXN = [xz_w | xn_w] (64x256), WIH = w_ih (320x384), WHH = w_hh (128x384).
#define OFF_XZXN 0        // 64x256   -> 16384
#define OFF_HZ   16384    // 128x128  -> 16384
#define OFF_HN   32768    // 128x128  -> 16384
#define OFF_PW1  49152    // 128x64   -> 8192
#define OFF_PW2  57344    // 64x64    -> 4096
#define OFF_WIH  61440    // 320x384  -> 122880
#define OFF_WHH  184320   // 128x384  -> 49152
#define BLOB_ELEMS 233472
#define INV_BYTE_OFF ((size_t)BLOB_ELEMS*2)
#define WJP_BYTE_OFF (INV_BYTE_OFF + 262144)   // float[32*51] repacked prep coeffs

// activation LDS strides (ushorts): stride_dw % 32 == 4 -> worst 2-way (free)
#define STRH 136
#define STRP 72
#define STRG 328
#define PFSTR 67          // fp32 p stride (floats)

// shared fp32 constant table offsets (floats)
#define SB_XZ    0
#define SB_XN    128
#define SB_P1    256
#define SB_P2    320
#define SB_BRZ   384      // b_ih+b_hh for r (0..127) and z (128..255)
#define SB_BIN   640      // b_ih n-chunk
#define SB_BHN   768      // b_hh n-chunk
#define SB_TOT   896

typedef float f4  __attribute__((ext_vector_type(4)));
typedef short bf8 __attribute__((ext_vector_type(8)));

__device__ __forceinline__ f4 mfma16(bf8 a, bf8 b, f4 c){
  return __builtin_amdgcn_mfma_f32_16x16x32_bf16(a,b,c,0,0,0);
}
__device__ __forceinline__ unsigned short f2bf(float f){
  unsigned int u = __builtin_bit_cast(unsigned int, f);
  u = (u + 0x7FFFu + ((u>>16)&1u)) >> 16;
  return (unsigned short)u;
}
__device__ __forceinline__ float sigmoidf_(float x){ return 1.f/(1.f+__expf(-x)); }
// column k -> ushort position inside a swizzled activation row (fragment order)
__device__ __forceinline__ int permk(int k){
  return ((k>>5)<<5) | (((k>>2)&3)<<3) | (((k>>4)&1)<<2) | (k&3);
}

// Wave-sliced GEMM: rows = NRT*16, wave owns col tiles {tile0 + s*8 : s<NSEL}
// of an NTT-tile-wide fragment blob. A from swizzled LDS (1 ds_read_b128 per
// row-tile per kc), B streamed from L2-resident global blob.
// unroll 2 caps the in-flight load window (anti-spill; R2/R3/R9 lesson).
template<int NKC,int NSEL,int NTT,int NRT>
__device__ __forceinline__ void gemmW(f4 (&acc)[NRT][NSEL], const unsigned short* Ald,
                                      int strideUsh, const unsigned short* __restrict__ Bg,
                                      int lane, int tile0){
  const int lc = lane & 15, a4 = lane >> 4;
  const unsigned short* a0 = Ald + lc*strideUsh + a4*8;
  const unsigned short* bl = Bg + (size_t)tile0*512 + lane*8;
  #pragma unroll 2
  for(int kc=0;kc<NKC;kc++){
    bf8 av0 = *(const bf8*)(a0 + kc*32);
    bf8 av1;
    if constexpr(NRT==2) av1 = *(const bf8*)(a0 + 16*strideUsh + kc*32);
    #pragma unroll
    for(int s=0;s<NSEL;s++){
      bf8 bv = *(const bf8*)(bl + (size_t)(kc*NTT + s*8)*512);
      acc[0][s] = mfma16(av0, bv, acc[0][s]);
      if constexpr(NRT==2) acc[1][s] = mfma16(av1, bv, acc[1][s]);
    }
  }
}

// ---------------- prep kernels ----------------
__global__ void init_inv(unsigned short* inv, float* outLoss){
  int i = blockIdx.x*256 + threadIdx.x;
  if(i < NT_*B_) inv[i] = 0xFFFFu;
  if(i == 0) *outLoss = 0.f;
}

__global__ void scatter_inv(unsigned short* inv, const int* __restrict__ obs){
  int i = blockIdx.x*256 + threadIdx.x;
  if(i < NT_*NO_){
    int t = i >> 12;
    int o = i & 4095;
    inv[(size_t)t*B_ + obs[i]] = (unsigned short)o;
  }
}

__global__ void build_blobs(const float* __restrict__ pw1, const float* __restrict__ pw2,
                            const float* __restrict__ xzw, const float* __restrict__ xnw,
                            const float* __restrict__ hzw, const float* __restrict__ hnw,
                            const float* __restrict__ wih, const float* __restrict__ whh,
                            const float* __restrict__ wprep, const float* __restrict__ bprep,
                            unsigned short* __restrict__ blob, float* __restrict__ wjp){
  int sec = blockIdx.y;
  int e = blockIdx.x*256 + threadIdx.x;
  if(sec==7){
    // repack w_prep [d][4][10] + bias_prep [d][10] -> wjp [d][pr][5], row stride 51
    // (51 dwords = odd mod 32 -> conflict-free LDS reads across 16 lanes)
    if(e < 32*51){
      int d = e/51, r = e%51, pr = r/5, c = r%5;
      float v = 0.f;
      if(pr < PREP_) v = (c<4) ? wprep[d*40 + c*10 + pr] : bprep[d*10 + pr];
      wjp[e] = v;
    }
    return;
  }
  const float* src=nullptr; int N, ld, off, cnt;
  switch(sec){
    case 0: src=nullptr; N=256; ld=0;   off=OFF_XZXN; cnt=16384;  break; // [xz|xn]
    case 1: src=hzw;  N=128; ld=128; off=OFF_HZ;   cnt=16384;  break;
    case 2: src=hnw;  N=128; ld=128; off=OFF_HN;   cnt=16384;  break;
    case 3: src=pw1;  N=64;  ld=64;  off=OFF_PW1;  cnt=8192;   break;
    case 4: src=pw2;  N=64;  ld=64;  off=OFF_PW2;  cnt=4096;   break;
    case 5: src=wih;  N=384; ld=384; off=OFF_WIH;  cnt=122880; break;
    default:src=whh;  N=384; ld=384; off=OFF_WHH;  cnt=49152;  break;
  }
  if(e >= cnt) return;
  int ntiles = N >> 4;
  int perkc = ntiles << 9;
  int kc = e / perkc, rem = e % perkc;
  int nt = rem >> 9, li = rem & 511;
  int lane = li >> 3, j = li & 7;
  int n = nt*16 + (lane & 15);
  int k = kc*32 + ((lane>>4)&3)*4 + (j&3) + ((j>>2)<<4);
  float v;
  if(sec==0) v = (n<128) ? xzw[(size_t)k*128+n] : xnw[(size_t)k*128 + (n-128)];
  else       v = src[(size_t)k*ld + n];
  blob[off + e] = f2bf(v);
}

// ---------------- fused persistent kernel ----------------
// 256 blocks x 512 threads (8 waves = 2 waves/SIMD); 32 rows/block (R5 config,
// best known). Wave w owns h-col slice [16w,16w+16) of every wide GEMM.
// R11 changes vs R5: (1) r,z gates accumulate gin@wih and h@whh into the SAME
// registers (only n keeps gi/gh split) -> peak acc 48->32 regs, kills the
// ~26MB/call scratch spill; (2) jump's prep coeffs read from stride-51 packed
// table -> kills the 8-way wprep bank conflicts (~60K cyc/CU).
__global__ __launch_bounds__(512,2) void fused(
    const float* __restrict__ X, const float* __restrict__ M,
    const float* __restrict__ cov,
    const float* __restrict__ cm_w1, const float* __restrict__ cm_b1,
    const float* __restrict__ cm_w2, const float* __restrict__ cm_b2,
    const float* __restrict__ p_b1, const float* __restrict__ p_b2,
    const float* __restrict__ xz_b, const float* __restrict__ xn_b,
    const float* __restrict__ b_ih, const float* __restrict__ b_hh,
    const unsigned short* __restrict__ blob, const float* __restrict__ wjp,
    const unsigned short* __restrict__ inv,
    float* __restrict__ outH, float* __restrict__ outP, float* __restrict__ outLoss)
{
  __shared__ __align__(16) unsigned short hb[32*STRH];   // bf16 h (swizzled)
  __shared__ __align__(16) unsigned short pb[32*STRP];   // bf16 p
  __shared__ __align__(16) unsigned short un[32*STRG];   // union: qb / zh / gin
  __shared__ __align__(16) float pf32[32*PFSTR];         // fp32 p
  __shared__ float sb[SB_TOT];
  __shared__ float sbJ[32*51];                           // packed prep coeffs
  __shared__ int obsO[32];
  __shared__ float lred[8];

  const int tid  = threadIdx.x;
  const int lane = tid & 63;
  const int w    = tid >> 6;           // wave 0..7
  const int lc   = lane & 15;
  const int a4   = lane >> 4;          // 0..3
  const int base = blockIdx.x * 32;
  float lsum = 0.f;

  // ---- stage fp32 constants ----
  for(int i=tid;i<128;i+=512){ sb[SB_XZ+i]=xz_b[i]; sb[SB_XN+i]=xn_b[i];
                               sb[SB_BIN+i]=b_ih[256+i]; sb[SB_BHN+i]=b_hh[256+i]; }
  for(int i=tid;i<64;i+=512){ sb[SB_P1+i]=p_b1[i]; sb[SB_P2+i]=p_b2[i]; }
  for(int i=tid;i<256;i+=512) sb[SB_BRZ+i]=b_ih[i]+b_hh[i];
  for(int i=tid;i<32*51;i+=512) sbJ[i]=wjp[i];

  // ---- init h = tanh(relu(cov@cm_w1+b1)@cm_w2+b2) (one-time scalar path) ----
  {
    float* c1f = pf32;                  // [32][36] scratch
    float* hInitF = (float*)un;         // [32][132] scratch
    int row = tid>>4, q = tid&15;
    float a[2];
    #pragma unroll
    for(int j=0;j<2;j++) a[j]=cm_b1[q*2+j];
    #pragma unroll
    for(int k=0;k<CS_;k++){
      float cv = cov[(size_t)(base+row)*CS_+k];
      #pragma unroll
      for(int j=0;j<2;j++) a[j] += cv*cm_w1[k*CH_+q*2+j];
    }
    #pragma unroll
    for(int j=0;j<2;j++) c1f[row*36+q*2+j] = fmaxf(a[j],0.f);
    __syncthreads();
    float acc2[8];
    #pragma unroll
    for(int j=0;j<8;j++) acc2[j]=cm_b2[q*8+j];
    for(int k=0;k<CH_;k++){
      float cv = c1f[row*36+k];
      #pragma unroll
      for(int j=0;j<8;j++) acc2[j] += cv*cm_w2[k*H_+q*8+j];
    }
    #pragma unroll
    for(int j=0;j<8;j++) hInitF[row*132+q*8+j] = tanhf(acc2[j]);
    __syncthreads();
  }

  f4 hFr[2];        // h cols [16w,16w+16), rows rt*16+a4*4+g
  f4 pFr;           // p rows prt*16+a4*4+g, col pct*16+lc
  const int prt = w & 1, pct = w >> 1;
  {
    float* hInitF = (float*)un;
    #pragma unroll
    for(int rt=0;rt<2;rt++)
      #pragma unroll
      for(int g=0;g<4;g++)
        hFr[rt][g] = hInitF[(rt*16+a4*4+g)*132 + w*16+lc];
    __syncthreads();                    // reads done before un reuse / hb write
    #pragma unroll
    for(int rt=0;rt<2;rt++)
      #pragma unroll
      for(int g=0;g<4;g++)
        hb[(rt*16+a4*4+g)*STRH + permk(w*16+lc)] = f2bf(hFr[rt][g]);
    __syncthreads();
  }

  // ---- p_model: wave w -> rows [16*prt), cols [16*pct) ----
  auto pmodel = [&](){
    f4 acc[1][1];
    { float bv = sb[SB_P1 + pct*16+lc]; f4 t={bv,bv,bv,bv}; acc[0][0]=t; }
    gemmW<4,1,4,1>(acc, hb + prt*16*STRH, STRH, blob+OFF_PW1, lane, pct);
    #pragma unroll
    for(int g=0;g<4;g++)
      un[(prt*16+a4*4+g)*STRP + permk(pct*16+lc)] = f2bf(fmaxf(acc[0][0][g],0.f));
    __syncthreads();
    { float bv = sb[SB_P2 + pct*16+lc]; f4 t={bv,bv,bv,bv}; acc[0][0]=t; }
    gemmW<2,1,4,1>(acc, un + prt*16*STRP, STRP, blob+OFF_PW2, lane, pct);
    pFr = acc[0][0];
    #pragma unroll
    for(int g=0;g<4;g++){
      int row = prt*16+a4*4+g, col = pct*16+lc;
      float v = acc[0][0][g];
      pb[row*STRP + permk(col)] = f2bf(v);
      pf32[row*PFSTR + col] = v;
    }
    __syncthreads();
  };

  // ---- euler: h += DT*(1-z)*(n-h); wave w owns h cols [16w,16w+16) ----
  auto euler = [&](){
    f4 ax[2][2];   // [rt][0]=xz part, [rt][1]=xn part (merged 256-wide blob)
    #pragma unroll
    for(int rt=0;rt<2;rt++){
      float bz = sb[SB_XZ + w*16+lc], bn = sb[SB_XN + w*16+lc];
      f4 tz={bz,bz,bz,bz}, tn={bn,bn,bn,bn};
      ax[rt][0]=tz; ax[rt][1]=tn;
    }
    gemmW<2,2,16,2>(ax, pb, STRP, blob+OFF_XZXN, lane, w);
    f4 ah[2][1]; { f4 z4={0.f,0.f,0.f,0.f}; ah[0][0]=z4; ah[1][0]=z4; }
    gemmW<4,1,8,2>(ah, hb, STRH, blob+OFF_HZ, lane, w);
    f4 zr[2];
    #pragma unroll
    for(int rt=0;rt<2;rt++)
      #pragma unroll
      for(int g=0;g<4;g++){
        float z = sigmoidf_(ax[rt][0][g] + ah[rt][0][g]);
        zr[rt][g]=z;
        un[(rt*16+a4*4+g)*STRH + permk(w*16+lc)] = f2bf(z*hFr[rt][g]);   // zh
      }
    __syncthreads();
    { f4 z4={0.f,0.f,0.f,0.f}; ah[0][0]=z4; ah[1][0]=z4; }
    gemmW<4,1,8,2>(ah, un, STRH, blob+OFF_HN, lane, w);
    #pragma unroll
    for(int rt=0;rt<2;rt++)
      #pragma unroll
      for(int g=0;g<4;g++){
        float nn = tanhf(ax[rt][1][g] + ah[rt][0][g]);
        float ho = hFr[rt][g];
        float hv = ho + DT_*(1.f-zr[rt][g])*(nn-ho);
        hFr[rt][g]=hv;
        hb[(rt*16+a4*4+g)*STRH + permk(w*16+lc)] = f2bf(hv);
      }
    __syncthreads();
  };

  // ---- Bayesian jump: r,z fused-accumulator; n split (tiles w,w+8,w+16) ----
  auto jump = [&](int t){
    if(tid < 32){
      unsigned short v = inv[(size_t)t*B_ + base + tid];
      obsO[tid] = (v == 0xFFFFu) ? -1 : (int)v;
    }
    __syncthreads();
    { // gin + loss: thread -> (row = tid>>4, d in {2q,2q+1})
      int row = tid>>4, q = tid&15, d0 = q*2;
      int o = obsO[row];
      float xa[2]={0.f,0.f}, ma[2]={0.f,0.f};
      if(o>=0){
        const float2 xv = *(const float2*)(X + ((size_t)t*NO_+o)*D_ + d0);
        const float2 mv = *(const float2*)(M + ((size_t)t*NO_+o)*D_ + d0);
        xa[0]=xv.x; xa[1]=xv.y; ma[0]=mv.x; ma[1]=mv.y;
      }
      #pragma unroll
      for(int j=0;j<2;j++){
        int d = d0+j;
        float mean = pf32[row*PFSTR + d];
        float lv   = pf32[row*PFSTR + D_ + d];
        float sg = __expf(0.5f*lv);
        float er = (xa[j]-mean)/sg;
        if(ma[j]>0.f) lsum += 0.5f*(er*er + lv + TWO_LOGC);
        const float* wj = sbJ + d*51;
        #pragma unroll
        for(int pr=0;pr<PREP_;pr++){
          const float* c = wj + pr*5;
          float s = xa[j]*c[0] + mean*c[1] + lv*c[2] + er*c[3] + c[4];
          s = fmaxf(s,0.f);
          un[row*STRG + permk(d*PREP_+pr)] = f2bf((ma[j]>0.f)? s : 0.f);  // gin
        }
      }
    }
    __syncthreads();
    // r,z: single accumulator for gin@wih + h@whh (+ summed biases)
    f4 rz[2][2];
    #pragma unroll
    for(int rt=0;rt<2;rt++){
      float br = sb[SB_BRZ + w*16+lc], bz = sb[SB_BRZ+128 + w*16+lc];
      f4 tr={br,br,br,br}, tz={bz,bz,bz,bz};
      rz[rt][0]=tr; rz[rt][1]=tz;
    }
    gemmW<10,2,24,2>(rz, un, STRG, blob+OFF_WIH, lane, w);
    gemmW<4,2,24,2> (rz, hb, STRH, blob+OFF_WHH, lane, w);
    // n: gi and gh kept separate (n = tanh(gi + r*gh))
    f4 ni[2][1], nh[2][1];
    #pragma unroll
    for(int rt=0;rt<2;rt++){
      float bin = sb[SB_BIN + w*16+lc], bhn = sb[SB_BHN + w*16+lc];
      f4 ti={bin,bin,bin,bin}, th={bhn,bhn,bhn,bhn};
      ni[rt][0]=ti; nh[rt][0]=th;
    }
    gemmW<10,1,24,2>(ni, un, STRG, blob+OFF_WIH, lane, w+16);
    gemmW<4,1,24,2> (nh, hb, STRH, blob+OFF_WHH, lane, w+16);
    __syncthreads();   // all waves done reading hb/un before conditional hb writes
    #pragma unroll
    for(int rt=0;rt<2;rt++)
      #pragma unroll
      for(int g=0;g<4;g++){
        int row = rt*16+a4*4+g;
        float r = sigmoidf_(rz[rt][0][g]);
        float z = sigmoidf_(rz[rt][1][g]);
        float nn = tanhf(ni[rt][0][g] + r*nh[rt][0][g]);
        float hv = (1.f-z)*nn + z*hFr[rt][g];
        if(obsO[row]>=0){
          hFr[rt][g]=hv;
          hb[row*STRH + permk(w*16+lc)] = f2bf(hv);
        }
      }
    __syncthreads();
  };

  // ---- sequence ----
  pmodel();
  for(int t=0;t<NT_;t++){
    euler();
    pmodel();
    jump(t);
    pmodel();
  }
  for(int it=0;it<NPOST_;it++){
    euler();
    pmodel();
  }

  // ---- outputs ----
  #pragma unroll
  for(int rt=0;rt<2;rt++)
    #pragma unroll
    for(int g=0;g<4;g++)
      outH[(size_t)(base + rt*16+a4*4+g)*H_ + w*16+lc] = hFr[rt][g];
  #pragma unroll
  for(int g=0;g<4;g++)
    outP[(size_t)(base + prt*16+a4*4+g)*(2*D_) + pct*16+lc] = pFr[g];

  #pragma unroll
  for(int off=32;off>0;off>>=1) lsum += __shfl_down(lsum, off);
  if(lane==0) lred[w]=lsum;
  __syncthreads();
  if(tid==0){
    float s = 0.f;
    #pragma unroll
    for(int i=0;i<8;i++) s += lred[i];
    atomicAdd(outLoss, s);
  }
}

// ---------------- launcher ----------------
extern "C" void kernel_launch(void* const* d_in, const int* in_sizes, int n_in,
                              void* d_out, int out_size, void* d_ws, size_t ws_size,
                              hipStream_t stream){
  const float* X      = (const float*)d_in[0];
  const float* M      = (const float*)d_in[1];
  const int*   obs    = (const int*)  d_in[2];
  const float* cov    = (const float*)d_in[3];
  const float* cm_w1  = (const float*)d_in[4];
  const float* cm_b1  = (const float*)d_in[5];
  const float* cm_w2  = (const float*)d_in[6];
  const float* cm_b2  = (const float*)d_in[7];
  const float* p_w1   = (const float*)d_in[8];
  const float* p_b1   = (const float*)d_in[9];
  const float* p_w2   = (const float*)d_in[10];
  const float* p_b2   = (const float*)d_in[11];
  const float* xz_w   = (const float*)d_in[12];
  const float* xz_b   = (const float*)d_in[13];
  const float* hz_w   = (const float*)d_in[14];
  const float* xn_w   = (const float*)d_in[15];
  const float* xn_b   = (const float*)d_in[16];
  const float* hn_w   = (const float*)d_in[17];
  const float* w_ih   = (const float*)d_in[18];
  const float* w_hh   = (const float*)d_in[19];
  const float* b_ih   = (const float*)d_in[20];
  const float* b_hh   = (const float*)d_in[21];
  const float* w_prep = (const float*)d_in[22];
  const float* bprep  = (const float*)d_in[23];

  unsigned short* blob = (unsigned short*)d_ws;
  unsigned short* inv  = (unsigned short*)((char*)d_ws + INV_BYTE_OFF);
  float*          wjp  = (float*)((char*)d_ws + WJP_BYTE_OFF);
  float* outH = (float*)d_out;
  float* outP = outH + (size_t)B_*H_;
  float* outLoss = outP + (size_t)B_*2*D_;

  init_inv   <<<dim3((NT_*B_+255)/256), dim3(256), 0, stream>>>(inv, outLoss);
  scatter_inv<<<dim3((NT_*NO_+255)/256), dim3(256), 0, stream>>>(inv, obs);
  build_blobs<<<dim3(480,8), dim3(256), 0, stream>>>(p_w1,p_w2,xz_w,xn_w,hz_w,hn_w,w_ih,w_hh,
                                                     w_prep,bprep, blob, wjp);
  fused      <<<dim3(B_/32), dim3(512), 0, stream>>>(
      X, M, cov, cm_w1, cm_b1, cm_w2, cm_b2, p_b1, p_b2, xz_b, xn_b,
      b_ih, b_hh, blob, wjp, inv, outH, outP, outLoss);
}

// Round 12
// 206.314 us; speedup vs baseline: 2.0844x; 1.0991x over previous
//
#include <hip/hip_runtime.h>

// ---------------- problem constants ----------------
#define B_     8192
#define D_     32
#define H_     128
#define PH_    64
#define PREP_  10
#define CS_    8
#define CH_    32
#define NT_    16
#define NO_    4096
#define NPOST_ 4
#define DT_    0.1f
#define TWO_LOGC 1.8378770664093453f   // 2*log(sqrt(2*pi))

// ---------------- bf16 fragment-blob offsets (ushort elements) ----------------
// blob layout for a KxN weight: element ((kc*ntiles+nt)*64+lane)*8+j holds
// W[kc*32 + 4*((lane>>4)&3) + (j&3) + 16*(j>>2)][nt*16 + (lane&15)]
// Merged: XZXN = [xz_w | xn_w] (64x256), WIH = w_ih (320x384), WHH = w_hh (128x384).
#define OFF_XZXN 0        // 64x256   -> 16384
#define OFF_HZ   16384    // 128x128  -> 16384
#define OFF_HN   32768    // 128x128  -> 16384
#define OFF_PW1  49152    // 128x64   -> 8192
#define OFF_PW2  57344    // 64x64    -> 4096
#define OFF_WIH  61440    // 320x384  -> 122880
#define OFF_WHH  184320   // 128x384  -> 49152
#define BLOB_ELEMS 233472
#define INV_BYTE_OFF ((size_t)BLOB_ELEMS*2)
#define WJP_BYTE_OFF (INV_BYTE_OFF + 262144)   // float[32*51] repacked prep coeffs

// LDS-resident weight copies (ushort offsets inside wlds)
#define WL_XZXN 0
#define WL_HZ   16384
#define WL_PW1  32768
#define WL_PW2  40960
#define WL_TOT  45056      // 88 KB

// activation LDS strides (ushorts): stride_dw % 32 == 4 -> worst 2-way (free)
#define STRH 136
#define STRP 72
#define STRG 328
#define PFSTR 67          // fp32 p stride (floats)

// shared fp32 constant table offsets (floats)
#define SB_XZ    0
#define SB_XN    128
#define SB_P1    256
#define SB_P2    320
#define SB_BRZ   384      // b_ih+b_hh for r (0..127) and z (128..255)
#define SB_BIN   640      // b_ih n-chunk
#define SB_BHN   768      // b_hh n-chunk
#define SB_TOT   896

typedef float f4  __attribute__((ext_vector_type(4)));
typedef short bf8 __attribute__((ext_vector_type(8)));

__device__ __forceinline__ f4 mfma16(bf8 a, bf8 b, f4 c){
  return __builtin_amdgcn_mfma_f32_16x16x32_bf16(a,b,c,0,0,0);
}
__device__ __forceinline__ unsigned short f2bf(float f){
  unsigned int u = __builtin_bit_cast(unsigned int, f);
  u = (u + 0x7FFFu + ((u>>16)&1u)) >> 16;
  return (unsigned short)u;
}
__device__ __forceinline__ float sigmoidf_(float x){ return 1.f/(1.f+__expf(-x)); }
// fast tanh: exact formula, 5 ops, saturates correctly (x->+inf: e=inf -> 1;
// x->-inf: e=0 -> -1). Replaces libm tanhf (~20+ ops) — VALUBusy was 39%.
__device__ __forceinline__ float tanhf_(float x){
  float e = __expf(2.f*x);
  return 1.f - 2.f/(e+1.f);
}
// column k -> ushort position inside a swizzled activation row (fragment order)
__device__ __forceinline__ int permk(int k){
  return ((k>>5)<<5) | (((k>>2)&3)<<3) | (((k>>4)&1)<<2) | (k&3);
}

// Wave-sliced GEMM: rows = NRT*16, wave owns col tiles {tile0 + s*8 : s<NSEL}
// of an NTT-tile-wide fragment blob. A from swizzled LDS (1 ds_read_b128 per
// row-tile per kc), B streamed from L2 blob OR LDS-resident copy (same layout).
// unroll 2 caps the in-flight load window (anti-spill; R2/R3/R9 lesson).
template<int NKC,int NSEL,int NTT,int NRT>
__device__ __forceinline__ void gemmW(f4 (&acc)[NRT][NSEL], const unsigned short* Ald,
                                      int strideUsh, const unsigned short* __restrict__ Bg,
                                      int lane, int tile0){
  const int lc = lane & 15, a4 = lane >> 4;
  const unsigned short* a0 = Ald + lc*strideUsh + a4*8;
  const unsigned short* bl = Bg + (size_t)tile0*512 + lane*8;
  #pragma unroll 2
  for(int kc=0;kc<NKC;kc++){
    bf8 av0 = *(const bf8*)(a0 + kc*32);
    bf8 av1;
    if constexpr(NRT==2) av1 = *(const bf8*)(a0 + 16*strideUsh + kc*32);
    #pragma unroll
    for(int s=0;s<NSEL;s++){
      bf8 bv = *(const bf8*)(bl + (size_t)(kc*NTT + s*8)*512);
      acc[0][s] = mfma16(av0, bv, acc[0][s]);
      if constexpr(NRT==2) acc[1][s] = mfma16(av1, bv, acc[1][s]);
    }
  }
}

// ---------------- prep kernels ----------------
__global__ void init_inv(unsigned short* inv, float* outLoss){
  int i = blockIdx.x*256 + threadIdx.x;
  if(i < NT_*B_) inv[i] = 0xFFFFu;
  if(i == 0) *outLoss = 0.f;
}

__global__ void scatter_inv(unsigned short* inv, const int* __restrict__ obs){
  int i = blockIdx.x*256 + threadIdx.x;
  if(i < NT_*NO_){
    int t = i >> 12;
    int o = i & 4095;
    inv[(size_t)t*B_ + obs[i]] = (unsigned short)o;
  }
}

__global__ void build_blobs(const float* __restrict__ pw1, const float* __restrict__ pw2,
                            const float* __restrict__ xzw, const float* __restrict__ xnw,
                            const float* __restrict__ hzw, const float* __restrict__ hnw,
                            const float* __restrict__ wih, const float* __restrict__ whh,
                            const float* __restrict__ wprep, const float* __restrict__ bprep,
                            unsigned short* __restrict__ blob, float* __restrict__ wjp){
  int sec = blockIdx.y;
  int e = blockIdx.x*256 + threadIdx.x;
  if(sec==7){
    // repack w_prep [d][4][10] + bias_prep [d][10] -> wjp [d][pr][5], row stride 51
    if(e < 32*51){
      int d = e/51, r = e%51, pr = r/5, c = r%5;
      float v = 0.f;
      if(pr < PREP_) v = (c<4) ? wprep[d*40 + c*10 + pr] : bprep[d*10 + pr];
      wjp[e] = v;
    }
    return;
  }
  const float* src=nullptr; int N, ld, off, cnt;
  switch(sec){
    case 0: src=nullptr; N=256; ld=0;   off=OFF_XZXN; cnt=16384;  break; // [xz|xn]
    case 1: src=hzw;  N=128; ld=128; off=OFF_HZ;   cnt=16384;  break;
    case 2: src=hnw;  N=128; ld=128; off=OFF_HN;   cnt=16384;  break;
    case 3: src=pw1;  N=64;  ld=64;  off=OFF_PW1;  cnt=8192;   break;
    case 4: src=pw2;  N=64;  ld=64;  off=OFF_PW2;  cnt=4096;   break;
    case 5: src=wih;  N=384; ld=384; off=OFF_WIH;  cnt=122880; break;
    default:src=whh;  N=384; ld=384; off=OFF_WHH;  cnt=49152;  break;
  }
  if(e >= cnt) return;
  int ntiles = N >> 4;
  int perkc = ntiles << 9;
  int kc = e / perkc, rem = e % perkc;
  int nt = rem >> 9, li = rem & 511;
  int lane = li >> 3, j = li & 7;
  int n = nt*16 + (lane & 15);
  int k = kc*32 + ((lane>>4)&3)*4 + (j&3) + ((j>>2)<<4);
  float v;
  if(sec==0) v = (n<128) ? xzw[(size_t)k*128+n] : xnw[(size_t)k*128 + (n-128)];
  else       v = src[(size_t)k*ld + n];
  blob[off + e] = f2bf(v);
}

// ---------------- fused persistent kernel ----------------
// 256 blocks x 512 threads (8 waves = 2 waves/SIMD); 32 rows/block.
// Wave w owns h-col slice [16w,16w+16) of every wide GEMM.
// R12 vs R11: (1) fast tanh; (2) PW1/PW2/XZXN/HZ staged ONCE into LDS (88KB,
// reused 16-20x) -> pmodel + euler-phase-1 become LDS-latency; (3) X/M jump
// gathers issued at top of t-loop (hide under euler+pmodel).
__global__ __launch_bounds__(512,2) void fused(
    const float* __restrict__ X, const float* __restrict__ M,
    const float* __restrict__ cov,
    const float* __restrict__ cm_w1, const float* __restrict__ cm_b1,
    const float* __restrict__ cm_w2, const float* __restrict__ cm_b2,
    const float* __restrict__ p_b1, const float* __restrict__ p_b2,
    const float* __restrict__ xz_b, const float* __restrict__ xn_b,
    const float* __restrict__ b_ih, const float* __restrict__ b_hh,
    const unsigned short* __restrict__ blob, const float* __restrict__ wjp,
    const unsigned short* __restrict__ inv,
    float* __restrict__ outH, float* __restrict__ outP, float* __restrict__ outLoss)
{
  __shared__ __align__(16) unsigned short wlds[WL_TOT];  // 88KB resident weights
  __shared__ __align__(16) unsigned short hb[32*STRH];   // bf16 h (swizzled)
  __shared__ __align__(16) unsigned short pb[32*STRP];   // bf16 p
  __shared__ __align__(16) unsigned short un[32*STRG];   // union: qb / zh / gin
  __shared__ __align__(16) float pf32[32*PFSTR];         // fp32 p
  __shared__ float sb[SB_TOT];
  __shared__ float sbJ[32*51];                           // packed prep coeffs
  __shared__ int obsO[32];
  __shared__ float lred[8];

  const int tid  = threadIdx.x;
  const int lane = tid & 63;
  const int w    = tid >> 6;           // wave 0..7
  const int lc   = lane & 15;
  const int a4   = lane >> 4;          // 0..3
  const int base = blockIdx.x * 32;
  float lsum = 0.f;

  // ---- stage fp32 constants + resident weights ----
  for(int i=tid;i<128;i+=512){ sb[SB_XZ+i]=xz_b[i]; sb[SB_XN+i]=xn_b[i];
                               sb[SB_BIN+i]=b_ih[256+i]; sb[SB_BHN+i]=b_hh[256+i]; }
  for(int i=tid;i<64;i+=512){ sb[SB_P1+i]=p_b1[i]; sb[SB_P2+i]=p_b2[i]; }
  for(int i=tid;i<256;i+=512) sb[SB_BRZ+i]=b_ih[i]+b_hh[i];
  for(int i=tid;i<32*51;i+=512) sbJ[i]=wjp[i];
  for(int i=tid*8;i<32768;i+=4096) *(uint4*)(wlds+i)      = *(const uint4*)(blob+i);        // XZXN|HZ
  for(int i=tid*8;i<12288;i+=4096) *(uint4*)(wlds+32768+i)= *(const uint4*)(blob+49152+i);  // PW1|PW2

  // ---- init h = tanh(relu(cov@cm_w1+b1)@cm_w2+b2) (one-time scalar path) ----
  {
    float* c1f = pf32;                  // [32][36] scratch
    float* hInitF = (float*)un;         // [32][132] scratch
    int row = tid>>4, q = tid&15;
    float a[2];
    #pragma unroll
    for(int j=0;j<2;j++) a[j]=cm_b1[q*2+j];
    #pragma unroll
    for(int k=0;k<CS_;k++){
      float cv = cov[(size_t)(base+row)*CS_+k];
      #pragma unroll
      for(int j=0;j<2;j++) a[j] += cv*cm_w1[k*CH_+q*2+j];
    }
    #pragma unroll
    for(int j=0;j<2;j++) c1f[row*36+q*2+j] = fmaxf(a[j],0.f);
    __syncthreads();
    float acc2[8];
    #pragma unroll
    for(int j=0;j<8;j++) acc2[j]=cm_b2[q*8+j];
    for(int k=0;k<CH_;k++){
      float cv = c1f[row*36+k];
      #pragma unroll
      for(int j=0;j<8;j++) acc2[j] += cv*cm_w2[k*H_+q*8+j];
    }
    #pragma unroll
    for(int j=0;j<8;j++) hInitF[row*132+q*8+j] = tanhf_(acc2[j]);
    __syncthreads();
  }

  f4 hFr[2];        // h cols [16w,16w+16), rows rt*16+a4*4+g
  f4 pFr;           // p rows prt*16+a4*4+g, col pct*16+lc
  const int prt = w & 1, pct = w >> 1;
  {
    float* hInitF = (float*)un;
    #pragma unroll
    for(int rt=0;rt<2;rt++)
      #pragma unroll
      for(int g=0;g<4;g++)
        hFr[rt][g] = hInitF[(rt*16+a4*4+g)*132 + w*16+lc];
    __syncthreads();                    // reads done before un reuse / hb write
    #pragma unroll
    for(int rt=0;rt<2;rt++)
      #pragma unroll
      for(int g=0;g<4;g++)
        hb[(rt*16+a4*4+g)*STRH + permk(w*16+lc)] = f2bf(hFr[rt][g]);
    __syncthreads();
  }

  // ---- p_model: wave w -> rows [16*prt), cols [16*pct); B from LDS ----
  auto pmodel = [&](){
    f4 acc[1][1];
    { float bv = sb[SB_P1 + pct*16+lc]; f4 t={bv,bv,bv,bv}; acc[0][0]=t; }
    gemmW<4,1,4,1>(acc, hb + prt*16*STRH, STRH, wlds+WL_PW1, lane, pct);
    #pragma unroll
    for(int g=0;g<4;g++)
      un[(prt*16+a4*4+g)*STRP + permk(pct*16+lc)] = f2bf(fmaxf(acc[0][0][g],0.f));
    __syncthreads();
    { float bv = sb[SB_P2 + pct*16+lc]; f4 t={bv,bv,bv,bv}; acc[0][0]=t; }
    gemmW<2,1,4,1>(acc, un + prt*16*STRP, STRP, wlds+WL_PW2, lane, pct);
    pFr = acc[0][0];
    #pragma unroll
    for(int g=0;g<4;g++){
      int row = prt*16+a4*4+g, col = pct*16+lc;
      float v = acc[0][0][g];
      pb[row*STRP + permk(col)] = f2bf(v);
      pf32[row*PFSTR + col] = v;
    }
    __syncthreads();
  };

  // ---- euler: h += DT*(1-z)*(n-h); XZXN+HZ from LDS, HN streamed ----
  auto euler = [&](){
    f4 ax[2][2];   // [rt][0]=xz part, [rt][1]=xn part (merged 256-wide blob)
    #pragma unroll
    for(int rt=0;rt<2;rt++){
      float bz = sb[SB_XZ + w*16+lc], bn = sb[SB_XN + w*16+lc];
      f4 tz={bz,bz,bz,bz}, tn={bn,bn,bn,bn};
      ax[rt][0]=tz; ax[rt][1]=tn;
    }
    gemmW<2,2,16,2>(ax, pb, STRP, wlds+WL_XZXN, lane, w);
    f4 ah[2][1]; { f4 z4={0.f,0.f,0.f,0.f}; ah[0][0]=z4; ah[1][0]=z4; }
    gemmW<4,1,8,2>(ah, hb, STRH, wlds+WL_HZ, lane, w);
    f4 zr[2];
    #pragma unroll
    for(int rt=0;rt<2;rt++)
      #pragma unroll
      for(int g=0;g<4;g++){
        float z = sigmoidf_(ax[rt][0][g] + ah[rt][0][g]);
        zr[rt][g]=z;
        un[(rt*16+a4*4+g)*STRH + permk(w*16+lc)] = f2bf(z*hFr[rt][g]);   // zh
      }
    __syncthreads();
    { f4 z4={0.f,0.f,0.f,0.f}; ah[0][0]=z4; ah[1][0]=z4; }
    gemmW<4,1,8,2>(ah, un, STRH, blob+OFF_HN, lane, w);
    #pragma unroll
    for(int rt=0;rt<2;rt++)
      #pragma unroll
      for(int g=0;g<4;g++){
        float nn = tanhf_(ax[rt][1][g] + ah[rt][0][g]);
        float ho = hFr[rt][g];
        float hv = ho + DT_*(1.f-zr[rt][g])*(nn-ho);
        hFr[rt][g]=hv;
        hb[(rt*16+a4*4+g)*STRH + permk(w*16+lc)] = f2bf(hv);
      }
    __syncthreads();
  };

  // ---- Bayesian jump: X/M prefetched by caller; r,z fused-acc; n split ----
  auto jump = [&](int o, float2 xv, float2 mv){
    { // gin + loss: thread -> (row = tid>>4, d in {2q,2q+1})
      int row = tid>>4, q = tid&15, d0 = q*2;
      if(q==0) obsO[row] = o;
      float xa[2]={xv.x,xv.y}, ma[2]={mv.x,mv.y};
      #pragma unroll
      for(int j=0;j<2;j++){
        int d = d0+j;
        float mean = pf32[row*PFSTR + d];
        float lv   = pf32[row*PFSTR + D_ + d];
        float sg = __expf(0.5f*lv);
        float er = (xa[j]-mean)/sg;
        if(ma[j]>0.f) lsum += 0.5f*(er*er + lv + TWO_LOGC);
        const float* wj = sbJ + d*51;
        #pragma unroll
        for(int pr=0;pr<PREP_;pr++){
          const float* c = wj + pr*5;
          float s = xa[j]*c[0] + mean*c[1] + lv*c[2] + er*c[3] + c[4];
          s = fmaxf(s,0.f);
          un[row*STRG + permk(d*PREP_+pr)] = f2bf((ma[j]>0.f)? s : 0.f);  // gin
        }
      }
    }
    __syncthreads();
    // r,z: single accumulator for gin@wih + h@whh (+ summed biases)
    f4 rz[2][2];
    #pragma unroll
    for(int rt=0;rt<2;rt++){
      float br = sb[SB_BRZ + w*16+lc], bz = sb[SB_BRZ+128 + w*16+lc];
      f4 tr={br,br,br,br}, tz={bz,bz,bz,bz};
      rz[rt][0]=tr; rz[rt][1]=tz;
    }
    gemmW<10,2,24,2>(rz, un, STRG, blob+OFF_WIH, lane, w);
    gemmW<4,2,24,2> (rz, hb, STRH, blob+OFF_WHH, lane, w);
    // n: gi and gh kept separate (n = tanh(gi + r*gh))
    f4 ni[2][1], nh[2][1];
    #pragma unroll
    for(int rt=0;rt<2;rt++){
      float bin = sb[SB_BIN + w*16+lc], bhn = sb[SB_BHN + w*16+lc];
      f4 ti={bin,bin,bin,bin}, th={bhn,bhn,bhn,bhn};
      ni[rt][0]=ti; nh[rt][0]=th;
    }
    gemmW<10,1,24,2>(ni, un, STRG, blob+OFF_WIH, lane, w+16);
    gemmW<4,1,24,2> (nh, hb, STRH, blob+OFF_WHH, lane, w+16);
    __syncthreads();   // all waves done reading hb/un before conditional hb writes
    #pragma unroll
    for(int rt=0;rt<2;rt++)
      #pragma unroll
      for(int g=0;g<4;g++){
        int row = rt*16+a4*4+g;
        float r = sigmoidf_(rz[rt][0][g]);
        float z = sigmoidf_(rz[rt][1][g]);
        float nn = tanhf_(ni[rt][0][g] + r*nh[rt][0][g]);
        float hv = (1.f-z)*nn + z*hFr[rt][g];
        if(obsO[row]>=0){
          hFr[rt][g]=hv;
          hb[row*STRH + permk(w*16+lc)] = f2bf(hv);
        }
      }
    __syncthreads();
  };

  // ---- sequence ----
  pmodel();
  for(int t=0;t<NT_;t++){
    // prefetch this t's jump gathers (consumed ~2 phases later)
    int prow = tid>>4, pq = tid&15;
    unsigned short iv = inv[(size_t)t*B_ + base + prow];
    int o = (iv==0xFFFFu)? -1 : (int)iv;
    float2 xv = make_float2(0.f,0.f), mv = make_float2(0.f,0.f);
    if(o>=0){
      xv = *(const float2*)(X + ((size_t)t*NO_+o)*D_ + pq*2);
      mv = *(const float2*)(M + ((size_t)t*NO_+o)*D_ + pq*2);
    }
    euler();
    pmodel();
    jump(o, xv, mv);
    pmodel();
  }
  for(int it=0;it<NPOST_;it++){
    euler();
    pmodel();
  }

  // ---- outputs ----
  #pragma unroll
  for(int rt=0;rt<2;rt++)
    #pragma unroll
    for(int g=0;g<4;g++)
      outH[(size_t)(base + rt*16+a4*4+g)*H_ + w*16+lc] = hFr[rt][g];
  #pragma unroll
  for(int g=0;g<4;g++)
    outP[(size_t)(base + prt*16+a4*4+g)*(2*D_) + pct*16+lc] = pFr[g];

  #pragma unroll
  for(int off=32;off>0;off>>=1) lsum += __shfl_down(lsum, off);
  if(lane==0) lred[w]=lsum;
  __syncthreads();
  if(tid==0){
    float s = 0.f;
    #pragma unroll
    for(int i=0;i<8;i++) s += lred[i];
    atomicAdd(outLoss, s);
  }
}

// ---------------- launcher ----------------
extern "C" void kernel_launch(void* const* d_in, const int* in_sizes, int n_in,
                              void* d_out, int out_size, void* d_ws, size_t ws_size,
                              hipStream_t stream){
  const float* X      = (const float*)d_in[0];
  const float* M      = (const float*)d_in[1];
  const int*   obs    = (const int*)  d_in[2];
  const float* cov    = (const float*)d_in[3];
  const float* cm_w1  = (const float*)d_in[4];
  const float* cm_b1  = (const float*)d_in[5];
  const float* cm_w2  = (const float*)d_in[6];
  const float* cm_b2  = (const float*)d_in[7];
  const float* p_w1   = (const float*)d_in[8];
  const float* p_b1   = (const float*)d_in[9];
  const float* p_w2   = (const float*)d_in[10];
  const float* p_b2   = (const float*)d_in[11];
  const float* xz_w   = (const float*)d_in[12];
  const float* xz_b   = (const float*)d_in[13];
  const float* hz_w   = (const float*)d_in[14];
  const float* xn_w   = (const float*)d_in[15];
  const float* xn_b   = (const float*)d_in[16];
  const float* hn_w   = (const float*)d_in[17];
  const float* w_ih   = (const float*)d_in[18];
  const float* w_hh   = (const float*)d_in[19];
  const float* b_ih   = (const float*)d_in[20];
  const float* b_hh   = (const float*)d_in[21];
  const float* w_prep = (const float*)d_in[22];
  const float* bprep  = (const float*)d_in[23];

  unsigned short* blob = (unsigned short*)d_ws;
  unsigned short* inv  = (unsigned short*)((char*)d_ws + INV_BYTE_OFF);
  float*          wjp  = (float*)((char*)d_ws + WJP_BYTE_OFF);
  float* outH = (float*)d_out;
  float* outP = outH + (size_t)B_*H_;
  float* outLoss = outP + (size_t)B_*2*D_;

  init_inv   <<<dim3((NT_*B_+255)/256), dim3(256), 0, stream>>>(inv, outLoss);
  scatter_inv<<<dim3((NT_*NO_+255)/256), dim3(256), 0, stream>>>(inv, obs);
  build_blobs<<<dim3(480,8), dim3(256), 0, stream>>>(p_w1,p_w2,xz_w,xn_w,hz_w,hn_w,w_ih,w_hh,
                                                     w_prep,bprep, blob, wjp);
  fused      <<<dim3(B_/32), dim3(512), 0, stream>>>(
      X, M, cov, cm_w1, cm_b1, cm_w2, cm_b2, p_b1, p_b2, xz_b, xn_b,
      b_ih, b_hh, blob, wjp, inv, outH, outP, outLoss);
}

// Round 13
// 199.503 us; speedup vs baseline: 2.1556x; 1.0341x over previous
//
#include <hip/hip_runtime.h>

// ---------------- problem constants ----------------
#define B_     8192
#define D_     32
#define H_     128
#define PH_    64
#define PREP_  10
#define CS_    8
#define CH_    32
#define NT_    16
#define NO_    4096
#define NPOST_ 4
#define DT_    0.1f
#define TWO_LOGC 1.8378770664093453f   // 2*log(sqrt(2*pi))

// ---------------- bf16 fragment-blob offsets (ushort elements) ----------------
// blob layout for a KxN weight: element ((kc*ntiles+nt)*64+lane)*8+j holds
// W[kc*32 + 4*((lane>>4)&3) + (j&3) + 16*(j>>2)][nt*16 + (lane&15)]
// Merged: XZXN = [xz_w | xn_w] (64x256), WIH = w_ih (320x384), WHH = w_hh (128x384).
#define OFF_XZXN 0        // 64x256   -> 16384
#define OFF_HZ   16384    // 128x128  -> 16384
#define OFF_HN   32768    // 128x128  -> 16384
#define OFF_PW1  49152    // 128x64   -> 8192
#define OFF_PW2  57344    // 64x64    -> 4096
#define OFF_WIH  61440    // 320x384  -> 122880
#define OFF_WHH  184320   // 128x384  -> 49152
#define BLOB_ELEMS 233472
#define INV_BYTE_OFF ((size_t)BLOB_ELEMS*2)
#define WJP_BYTE_OFF (INV_BYTE_OFF + 262144)   // float[32*51] repacked prep coeffs

// LDS-resident weight copies (ushort offsets inside wlds)
#define WL_XZXN 0
#define WL_HZ   16384
#define WL_PW1  32768
#define WL_PW2  40960
#define WL_TOT  45056      // 88 KB

// activation LDS strides (ushorts): stride_dw % 32 == 4 -> worst 2-way (free)
#define STRH 136
#define STRP 72
#define STRG 328
#define PFSTR 67          // fp32 p stride (floats)

// shared fp32 constant table offsets (floats)
#define SB_XZ    0
#define SB_XN    128
#define SB_P1    256
#define SB_P2    320
#define SB_BRZ   384      // b_ih+b_hh for r (0..127) and z (128..255)
#define SB_BIN   640      // b_ih n-chunk
#define SB_BHN   768      // b_hh n-chunk
#define SB_TOT   896

typedef float f4  __attribute__((ext_vector_type(4)));
typedef short bf8 __attribute__((ext_vector_type(8)));

__device__ __forceinline__ f4 mfma16(bf8 a, bf8 b, f4 c){
  return __builtin_amdgcn_mfma_f32_16x16x32_bf16(a,b,c,0,0,0);
}
__device__ __forceinline__ unsigned short f2bf(float f){
  unsigned int u = __builtin_bit_cast(unsigned int, f);
  u = (u + 0x7FFFu + ((u>>16)&1u)) >> 16;
  return (unsigned short)u;
}
__device__ __forceinline__ float sigmoidf_(float x){ return 1.f/(1.f+__expf(-x)); }
// fast tanh: exact formula, 5 ops, saturates correctly.
__device__ __forceinline__ float tanhf_(float x){
  float e = __expf(2.f*x);
  return 1.f - 2.f/(e+1.f);
}
// column k -> ushort position inside a swizzled activation row (fragment order)
__device__ __forceinline__ int permk(int k){
  return ((k>>5)<<5) | (((k>>2)&3)<<3) | (((k>>4)&1)<<2) | (k&3);
}

// Wave-sliced GEMM: rows = NRT*16, wave owns col tiles {tile0 + s*8 : s<NSEL}
// of an NTT-tile-wide fragment blob. A from swizzled LDS (1 ds_read_b128 per
// row-tile per kc), B streamed from L2 blob OR LDS-resident copy (same layout).
// unroll 2 caps the in-flight load window (anti-spill; R2/R3/R9 lesson).
template<int NKC,int NSEL,int NTT,int NRT>
__device__ __forceinline__ void gemmW(f4 (&acc)[NRT][NSEL], const unsigned short* Ald,
                                      int strideUsh, const unsigned short* __restrict__ Bg,
                                      int lane, int tile0){
  const int lc = lane & 15, a4 = lane >> 4;
  const unsigned short* a0 = Ald + lc*strideUsh + a4*8;
  const unsigned short* bl = Bg + (size_t)tile0*512 + lane*8;
  #pragma unroll 2
  for(int kc=0;kc<NKC;kc++){
    bf8 av0 = *(const bf8*)(a0 + kc*32);
    bf8 av1;
    if constexpr(NRT==2) av1 = *(const bf8*)(a0 + 16*strideUsh + kc*32);
    #pragma unroll
    for(int s=0;s<NSEL;s++){
      bf8 bv = *(const bf8*)(bl + (size_t)(kc*NTT + s*8)*512);
      acc[0][s] = mfma16(av0, bv, acc[0][s]);
      if constexpr(NRT==2) acc[1][s] = mfma16(av1, bv, acc[1][s]);
    }
  }
}

// ---------------- prep kernels ----------------
__global__ void init_inv(unsigned short* inv, float* outLoss){
  int i = blockIdx.x*256 + threadIdx.x;
  if(i < NT_*B_) inv[i] = 0xFFFFu;
  if(i == 0) *outLoss = 0.f;
}

__global__ void scatter_inv(unsigned short* inv, const int* __restrict__ obs){
  int i = blockIdx.x*256 + threadIdx.x;
  if(i < NT_*NO_){
    int t = i >> 12;
    int o = i & 4095;
    inv[(size_t)t*B_ + obs[i]] = (unsigned short)o;
  }
}

__global__ void build_blobs(const float* __restrict__ pw1, const float* __restrict__ pw2,
                            const float* __restrict__ xzw, const float* __restrict__ xnw,
                            const float* __restrict__ hzw, const float* __restrict__ hnw,
                            const float* __restrict__ wih, const float* __restrict__ whh,
                            const float* __restrict__ wprep, const float* __restrict__ bprep,
                            unsigned short* __restrict__ blob, float* __restrict__ wjp){
  int sec = blockIdx.y;
  int e = blockIdx.x*256 + threadIdx.x;
  if(sec==7){
    // repack w_prep [d][4][10] + bias_prep [d][10] -> wjp [d][pr][5], row stride 51
    if(e < 32*51){
      int d = e/51, r = e%51, pr = r/5, c = r%5;
      float v = 0.f;
      if(pr < PREP_) v = (c<4) ? wprep[d*40 + c*10 + pr] : bprep[d*10 + pr];
      wjp[e] = v;
    }
    return;
  }
  const float* src=nullptr; int N, ld, off, cnt;
  switch(sec){
    case 0: src=nullptr; N=256; ld=0;   off=OFF_XZXN; cnt=16384;  break; // [xz|xn]
    case 1: src=hzw;  N=128; ld=128; off=OFF_HZ;   cnt=16384;  break;
    case 2: src=hnw;  N=128; ld=128; off=OFF_HN;   cnt=16384;  break;
    case 3: src=pw1;  N=64;  ld=64;  off=OFF_PW1;  cnt=8192;   break;
    case 4: src=pw2;  N=64;  ld=64;  off=OFF_PW2;  cnt=4096;   break;
    case 5: src=wih;  N=384; ld=384; off=OFF_WIH;  cnt=122880; break;
    default:src=whh;  N=384; ld=384; off=OFF_WHH;  cnt=49152;  break;
  }
  if(e >= cnt) return;
  int ntiles = N >> 4;
  int perkc = ntiles << 9;
  int kc = e / perkc, rem = e % perkc;
  int nt = rem >> 9, li = rem & 511;
  int lane = li >> 3, j = li & 7;
  int n = nt*16 + (lane & 15);
  int k = kc*32 + ((lane>>4)&3)*4 + (j&3) + ((j>>2)<<4);
  float v;
  if(sec==0) v = (n<128) ? xzw[(size_t)k*128+n] : xnw[(size_t)k*128 + (n-128)];
  else       v = src[(size_t)k*ld + n];
  blob[off + e] = f2bf(v);
}

// ---------------- fused persistent kernel ----------------
// 256 blocks x 512 threads (8 waves = 2 waves/SIMD); 32 rows/block.
// R13 vs R12: (1) jump gates re-merged into 3-wide GEMMs (halves jump A-reads,
// 12 MFMAs per load batch) — VGPR 88 leaves room; (2) euler's HN B-fragments
// prefetched into registers before phase 1 (T14 issue-early); (3) er via
// exp(-0.5lv)*diff (no divide), masked loss via multiply.
__global__ __launch_bounds__(512,2) void fused(
    const float* __restrict__ X, const float* __restrict__ M,
    const float* __restrict__ cov,
    const float* __restrict__ cm_w1, const float* __restrict__ cm_b1,
    const float* __restrict__ cm_w2, const float* __restrict__ cm_b2,
    const float* __restrict__ p_b1, const float* __restrict__ p_b2,
    const float* __restrict__ xz_b, const float* __restrict__ xn_b,
    const float* __restrict__ b_ih, const float* __restrict__ b_hh,
    const unsigned short* __restrict__ blob, const float* __restrict__ wjp,
    const unsigned short* __restrict__ inv,
    float* __restrict__ outH, float* __restrict__ outP, float* __restrict__ outLoss)
{
  __shared__ __align__(16) unsigned short wlds[WL_TOT];  // 88KB resident weights
  __shared__ __align__(16) unsigned short hb[32*STRH];   // bf16 h (swizzled)
  __shared__ __align__(16) unsigned short pb[32*STRP];   // bf16 p
  __shared__ __align__(16) unsigned short un[32*STRG];   // union: qb / zh / gin
  __shared__ __align__(16) float pf32[32*PFSTR];         // fp32 p
  __shared__ float sb[SB_TOT];
  __shared__ float sbJ[32*51];                           // packed prep coeffs
  __shared__ int obsO[32];
  __shared__ float lred[8];

  const int tid  = threadIdx.x;
  const int lane = tid & 63;
  const int w    = tid >> 6;           // wave 0..7
  const int lc   = lane & 15;
  const int a4   = lane >> 4;          // 0..3
  const int base = blockIdx.x * 32;
  float lsum = 0.f;

  // ---- stage fp32 constants + resident weights ----
  for(int i=tid;i<128;i+=512){ sb[SB_XZ+i]=xz_b[i]; sb[SB_XN+i]=xn_b[i];
                               sb[SB_BIN+i]=b_ih[256+i]; sb[SB_BHN+i]=b_hh[256+i]; }
  for(int i=tid;i<64;i+=512){ sb[SB_P1+i]=p_b1[i]; sb[SB_P2+i]=p_b2[i]; }
  for(int i=tid;i<256;i+=512) sb[SB_BRZ+i]=b_ih[i]+b_hh[i];
  for(int i=tid;i<32*51;i+=512) sbJ[i]=wjp[i];
  for(int i=tid*8;i<32768;i+=4096) *(uint4*)(wlds+i)      = *(const uint4*)(blob+i);        // XZXN|HZ
  for(int i=tid*8;i<12288;i+=4096) *(uint4*)(wlds+32768+i)= *(const uint4*)(blob+49152+i);  // PW1|PW2

  // ---- init h = tanh(relu(cov@cm_w1+b1)@cm_w2+b2) (one-time scalar path) ----
  {
    float* c1f = pf32;                  // [32][36] scratch
    float* hInitF = (float*)un;         // [32][132] scratch
    int row = tid>>4, q = tid&15;
    float a[2];
    #pragma unroll
    for(int j=0;j<2;j++) a[j]=cm_b1[q*2+j];
    #pragma unroll
    for(int k=0;k<CS_;k++){
      float cv = cov[(size_t)(base+row)*CS_+k];
      #pragma unroll
      for(int j=0;j<2;j++) a[j] += cv*cm_w1[k*CH_+q*2+j];
    }
    #pragma unroll
    for(int j=0;j<2;j++) c1f[row*36+q*2+j] = fmaxf(a[j],0.f);
    __syncthreads();
    float acc2[8];
    #pragma unroll
    for(int j=0;j<8;j++) acc2[j]=cm_b2[q*8+j];
    for(int k=0;k<CH_;k++){
      float cv = c1f[row*36+k];
      #pragma unroll
      for(int j=0;j<8;j++) acc2[j] += cv*cm_w2[k*H_+q*8+j];
    }
    #pragma unroll
    for(int j=0;j<8;j++) hInitF[row*132+q*8+j] = tanhf_(acc2[j]);
    __syncthreads();
  }

  f4 hFr[2];        // h cols [16w,16w+16), rows rt*16+a4*4+g
  f4 pFr;           // p rows prt*16+a4*4+g, col pct*16+lc
  const int prt = w & 1, pct = w >> 1;
  {
    float* hInitF = (float*)un;
    #pragma unroll
    for(int rt=0;rt<2;rt++)
      #pragma unroll
      for(int g=0;g<4;g++)
        hFr[rt][g] = hInitF[(rt*16+a4*4+g)*132 + w*16+lc];
    __syncthreads();                    // reads done before un reuse / hb write
    #pragma unroll
    for(int rt=0;rt<2;rt++)
      #pragma unroll
      for(int g=0;g<4;g++)
        hb[(rt*16+a4*4+g)*STRH + permk(w*16+lc)] = f2bf(hFr[rt][g]);
    __syncthreads();
  }

  // ---- p_model: wave w -> rows [16*prt), cols [16*pct); B from LDS ----
  auto pmodel = [&](){
    f4 acc[1][1];
    { float bv = sb[SB_P1 + pct*16+lc]; f4 t={bv,bv,bv,bv}; acc[0][0]=t; }
    gemmW<4,1,4,1>(acc, hb + prt*16*STRH, STRH, wlds+WL_PW1, lane, pct);
    #pragma unroll
    for(int g=0;g<4;g++)
      un[(prt*16+a4*4+g)*STRP + permk(pct*16+lc)] = f2bf(fmaxf(acc[0][0][g],0.f));
    __syncthreads();
    { float bv = sb[SB_P2 + pct*16+lc]; f4 t={bv,bv,bv,bv}; acc[0][0]=t; }
    gemmW<2,1,4,1>(acc, un + prt*16*STRP, STRP, wlds+WL_PW2, lane, pct);
    pFr = acc[0][0];
    #pragma unroll
    for(int g=0;g<4;g++){
      int row = prt*16+a4*4+g, col = pct*16+lc;
      float v = acc[0][0][g];
      pb[row*STRP + permk(col)] = f2bf(v);
      pf32[row*PFSTR + col] = v;
    }
    __syncthreads();
  };

  // ---- euler: h += DT*(1-z)*(n-h); XZXN+HZ from LDS; HN prefetched to regs ----
  auto euler = [&](){
    // T14 issue-early: HN B-fragments (L2) in flight across phase 1 + barrier
    bf8 hnB[4];
    #pragma unroll
    for(int kc=0;kc<4;kc++)
      hnB[kc] = *(const bf8*)(blob + OFF_HN + (size_t)(kc*8+w)*512 + lane*8);
    f4 ax[2][2];   // [rt][0]=xz part, [rt][1]=xn part (merged 256-wide blob)
    #pragma unroll
    for(int rt=0;rt<2;rt++){
      float bz = sb[SB_XZ + w*16+lc], bn = sb[SB_XN + w*16+lc];
      f4 tz={bz,bz,bz,bz}, tn={bn,bn,bn,bn};
      ax[rt][0]=tz; ax[rt][1]=tn;
    }
    gemmW<2,2,16,2>(ax, pb, STRP, wlds+WL_XZXN, lane, w);
    f4 ah[2][1]; { f4 z4={0.f,0.f,0.f,0.f}; ah[0][0]=z4; ah[1][0]=z4; }
    gemmW<4,1,8,2>(ah, hb, STRH, wlds+WL_HZ, lane, w);
    f4 zr[2];
    #pragma unroll
    for(int rt=0;rt<2;rt++)
      #pragma unroll
      for(int g=0;g<4;g++){
        float z = sigmoidf_(ax[rt][0][g] + ah[rt][0][g]);
        zr[rt][g]=z;
        un[(rt*16+a4*4+g)*STRH + permk(w*16+lc)] = f2bf(z*hFr[rt][g]);   // zh
      }
    __syncthreads();
    // ah2 = zh @ HN with the prefetched B fragments
    f4 ah2[2]; { f4 z4={0.f,0.f,0.f,0.f}; ah2[0]=z4; ah2[1]=z4; }
    {
      const unsigned short* a0 = un + lc*STRH + a4*8;
      #pragma unroll
      for(int kc=0;kc<4;kc++){
        bf8 av0 = *(const bf8*)(a0 + kc*32);
        bf8 av1 = *(const bf8*)(a0 + 16*STRH + kc*32);
        ah2[0] = mfma16(av0, hnB[kc], ah2[0]);
        ah2[1] = mfma16(av1, hnB[kc], ah2[1]);
      }
    }
    #pragma unroll
    for(int rt=0;rt<2;rt++)
      #pragma unroll
      for(int g=0;g<4;g++){
        float nn = tanhf_(ax[rt][1][g] + ah2[rt][g]);
        float ho = hFr[rt][g];
        float hv = ho + DT_*(1.f-zr[rt][g])*(nn-ho);
        hFr[rt][g]=hv;
        hb[(rt*16+a4*4+g)*STRH + permk(w*16+lc)] = f2bf(hv);
      }
    __syncthreads();
  };

  // ---- Bayesian jump: merged 3-gate GEMMs (tiles {w, w+8, w+16}) ----
  auto jump = [&](int o, float2 xv, float2 mv){
    { // gin + loss: thread -> (row = tid>>4, d in {2q,2q+1})
      int row = tid>>4, q = tid&15, d0 = q*2;
      if(q==0) obsO[row] = o;
      float xa[2]={xv.x,xv.y}, ma[2]={mv.x,mv.y};
      #pragma unroll
      for(int j=0;j<2;j++){
        int d = d0+j;
        float mean = pf32[row*PFSTR + d];
        float lv   = pf32[row*PFSTR + D_ + d];
        float isg = __expf(-0.5f*lv);
        float er = (xa[j]-mean)*isg;
        lsum += 0.5f*(er*er + lv + TWO_LOGC)*ma[j];   // mask is exactly 0/1
        const float* wj = sbJ + d*51;
        #pragma unroll
        for(int pr=0;pr<PREP_;pr++){
          const float* c = wj + pr*5;
          float s = xa[j]*c[0] + mean*c[1] + lv*c[2] + er*c[3] + c[4];
          s = fmaxf(s,0.f);
          un[row*STRG + permk(d*PREP_+pr)] = f2bf(s*ma[j]);  // gin (masked)
        }
      }
    }
    __syncthreads();
    // gi = gin @ [wih_r|wih_z|wih_n] (+biases); gh = h @ [whh_r|whh_z|whh_n]
    f4 gi[2][3];
    #pragma unroll
    for(int rt=0;rt<2;rt++){
      float br = sb[SB_BRZ + w*16+lc], bz = sb[SB_BRZ+128 + w*16+lc], bn = sb[SB_BIN + w*16+lc];
      f4 tr={br,br,br,br}, tz={bz,bz,bz,bz}, tn={bn,bn,bn,bn};
      gi[rt][0]=tr; gi[rt][1]=tz; gi[rt][2]=tn;
    }
    gemmW<10,3,24,2>(gi, un, STRG, blob+OFF_WIH, lane, w);
    f4 gh[2][3];
    #pragma unroll
    for(int rt=0;rt<2;rt++){
      float bhn = sb[SB_BHN + w*16+lc];
      f4 z4={0.f,0.f,0.f,0.f}, tn={bhn,bhn,bhn,bhn};
      gh[rt][0]=z4; gh[rt][1]=z4; gh[rt][2]=tn;
    }
    gemmW<4,3,24,2>(gh, hb, STRH, blob+OFF_WHH, lane, w);
    __syncthreads();   // all waves done reading hb/un before conditional hb writes
    #pragma unroll
    for(int rt=0;rt<2;rt++)
      #pragma unroll
      for(int g=0;g<4;g++){
        int row = rt*16+a4*4+g;
        float r = sigmoidf_(gi[rt][0][g] + gh[rt][0][g]);
        float z = sigmoidf_(gi[rt][1][g] + gh[rt][1][g]);
        float nn = tanhf_(gi[rt][2][g] + r*gh[rt][2][g]);
        float hv = (1.f-z)*nn + z*hFr[rt][g];
        if(obsO[row]>=0){
          hFr[rt][g]=hv;
          hb[row*STRH + permk(w*16+lc)] = f2bf(hv);
        }
      }
    __syncthreads();
  };

  // ---- sequence ----
  pmodel();
  for(int t=0;t<NT_;t++){
    // prefetch this t's jump gathers (consumed ~2 phases later)
    int prow = tid>>4, pq = tid&15;
    unsigned short iv = inv[(size_t)t*B_ + base + prow];
    int o = (iv==0xFFFFu)? -1 : (int)iv;
    float2 xv = make_float2(0.f,0.f), mv = make_float2(0.f,0.f);
    if(o>=0){
      xv = *(const float2*)(X + ((size_t)t*NO_+o)*D_ + pq*2);
      mv = *(const float2*)(M + ((size_t)t*NO_+o)*D_ + pq*2);
    }
    euler();
    pmodel();
    jump(o, xv, mv);
    pmodel();
  }
  for(int it=0;it<NPOST_;it++){
    euler();
    pmodel();
  }

  // ---- outputs ----
  #pragma unroll
  for(int rt=0;rt<2;rt++)
    #pragma unroll
    for(int g=0;g<4;g++)
      outH[(size_t)(base + rt*16+a4*4+g)*H_ + w*16+lc] = hFr[rt][g];
  #pragma unroll
  for(int g=0;g<4;g++)
    outP[(size_t)(base + prt*16+a4*4+g)*(2*D_) + pct*16+lc] = pFr[g];

  #pragma unroll
  for(int off=32;off>0;off>>=1) lsum += __shfl_down(lsum, off);
  if(lane==0) lred[w]=lsum;
  __syncthreads();
  if(tid==0){
    float s = 0.f;
    #pragma unroll
    for(int i=0;i<8;i++) s += lred[i];
    atomicAdd(outLoss, s);
  }
}

// ---------------- launcher ----------------
extern "C" void kernel_launch(void* const* d_in, const int* in_sizes, int n_in,
                              void* d_out, int out_size, void* d_ws, size_t ws_size,
                              hipStream_t stream){
  const float* X      = (const float*)d_in[0];
  const float* M      = (const float*)d_in[1];
  const int*   obs    = (const int*)  d_in[2];
  const float* cov    = (const float*)d_in[3];
  const float* cm_w1  = (const float*)d_in[4];
  const float* cm_b1  = (const float*)d_in[5];
  const float* cm_w2  = (const float*)d_in[6];
  const float* cm_b2  = (const float*)d_in[7];
  const float* p_w1   = (const float*)d_in[8];
  const float* p_b1   = (const float*)d_in[9];
  const float* p_w2   = (const float*)d_in[10];
  const float* p_b2   = (const float*)d_in[11];
  const float* xz_w   = (const float*)d_in[12];
  const float* xz_b   = (const float*)d_in[13];
  const float* hz_w   = (const float*)d_in[14];
  const float* xn_w   = (const float*)d_in[15];
  const float* xn_b   = (const float*)d_in[16];
  const float* hn_w   = (const float*)d_in[17];
  const float* w_ih   = (const float*)d_in[18];
  const float* w_hh   = (const float*)d_in[19];
  const float* b_ih   = (const float*)d_in[20];
  const float* b_hh   = (const float*)d_in[21];
  const float* w_prep = (const float*)d_in[22];
  const float* bprep  = (const float*)d_in[23];

  unsigned short* blob = (unsigned short*)d_ws;
  unsigned short* inv  = (unsigned short*)((char*)d_ws + INV_BYTE_OFF);
  float*          wjp  = (float*)((char*)d_ws + WJP_BYTE_OFF);
  float* outH = (float*)d_out;
  float* outP = outH + (size_t)B_*H_;
  float* outLoss = outP + (size_t)B_*2*D_;

  init_inv   <<<dim3((NT_*B_+255)/256), dim3(256), 0, stream>>>(inv, outLoss);
  scatter_inv<<<dim3((NT_*NO_+255)/256), dim3(256), 0, stream>>>(inv, obs);
  build_blobs<<<dim3(480,8), dim3(256), 0, stream>>>(p_w1,p_w2,xz_w,xn_w,hz_w,hn_w,w_ih,w_hh,
                                                     w_prep,bprep, blob, wjp);
  fused      <<<dim3(B_/32), dim3(512), 0, stream>>>(
      X, M, cov, cm_w1, cm_b1, cm_w2, cm_b2, p_b1, p_b2, xz_b, xn_b,
      b_ih, b_hh, blob, wjp, inv, outH, outP, outLoss);
}

// Round 14
// 189.429 us; speedup vs baseline: 2.2702x; 1.0532x over previous
//
#include <hip/hip_runtime.h>

// ---------------- problem constants ----------------
#define B_     8192
#define D_     32
#define H_     128
#define PH_    64
#define PREP_  10
#define CS_    8
#define CH_    32
#define NT_    16
#define NO_    4096
#define NPOST_ 4
#define DT_    0.1f
#define TWO_LOGC 1.8378770664093453f   // 2*log(sqrt(2*pi))

// ---------------- bf16 fragment-blob offsets (ushort elements) ----------------
// blob layout for a KxN weight: element ((kc*ntiles+nt)*64+lane)*8+j holds
// W[kc*32 + 4*((lane>>4)&3) + (j&3) + 16*(j>>2)][nt*16 + (lane&15)]
// Merged: XZXN = [xz_w | xn_w] (64x256), WIH = w_ih (320x384), WHH = w_hh (128x384).
#define OFF_XZXN 0        // 64x256   -> 16384
#define OFF_HZ   16384    // 128x128  -> 16384
#define OFF_HN   32768    // 128x128  -> 16384
#define OFF_PW1  49152    // 128x64   -> 8192
#define OFF_PW2  57344    // 64x64    -> 4096
#define OFF_WIH  61440    // 320x384  -> 122880
#define OFF_WHH  184320   // 128x384  -> 49152
#define BLOB_ELEMS 233472
#define INV_BYTE_OFF ((size_t)BLOB_ELEMS*2)
#define WJP_BYTE_OFF (INV_BYTE_OFF + 262144)   // float[32*51] repacked prep coeffs

// LDS-resident weight copies (ushort offsets inside wlds)
#define WL_XZXN 0
#define WL_HZ   16384
#define WL_PW1  32768
#define WL_PW2  40960
#define WL_TOT  45056      // 88 KB

// activation LDS strides (ushorts): stride_dw % 32 == 4 -> worst 2-way (free)
#define STRH 136
#define STRP 72
#define STRG 328
#define PFSTR 67          // fp32 p stride (floats)

// shared fp32 constant table offsets (floats)
#define SB_XZ    0
#define SB_XN    128
#define SB_P1    256
#define SB_P2    320
#define SB_BRZ   384      // b_ih+b_hh for r (0..127) and z (128..255)
#define SB_BIN   640      // b_ih n-chunk
#define SB_BHN   768      // b_hh n-chunk
#define SB_TOT   896

typedef float f4  __attribute__((ext_vector_type(4)));
typedef short bf8 __attribute__((ext_vector_type(8)));

__device__ __forceinline__ f4 mfma16(bf8 a, bf8 b, f4 c){
  return __builtin_amdgcn_mfma_f32_16x16x32_bf16(a,b,c,0,0,0);
}
__device__ __forceinline__ unsigned short f2bf(float f){
  unsigned int u = __builtin_bit_cast(unsigned int, f);
  u = (u + 0x7FFFu + ((u>>16)&1u)) >> 16;
  return (unsigned short)u;
}
// pack 2 floats -> 2 bf16 (RNE) in one op
__device__ __forceinline__ unsigned int cvtpk(float lo, float hi){
  unsigned int r;
  asm("v_cvt_pk_bf16_f32 %0, %1, %2" : "=v"(r) : "v"(lo), "v"(hi));
  return r;
}
__device__ __forceinline__ float sigmoidf_(float x){ return 1.f/(1.f+__expf(-x)); }
// fast tanh: exact formula, 5 ops, saturates correctly.
__device__ __forceinline__ float tanhf_(float x){
  float e = __expf(2.f*x);
  return 1.f - 2.f/(e+1.f);
}
// column k -> ushort position inside a swizzled activation row (fragment order)
__device__ __forceinline__ int permk(int k){
  return ((k>>5)<<5) | (((k>>2)&3)<<3) | (((k>>4)&1)<<2) | (k&3);
}

// Wave-sliced GEMM: rows = NRT*16, wave owns col tiles {tile0 + s*8 : s<NSEL}
// of an NTT-tile-wide fragment blob. A from swizzled LDS (1 ds_read_b128 per
// row-tile per kc), B streamed from L2 blob OR LDS-resident copy (same layout).
// unroll 2 caps the in-flight load window (anti-spill; R2/R3/R9 lesson).
template<int NKC,int NSEL,int NTT,int NRT>
__device__ __forceinline__ void gemmW(f4 (&acc)[NRT][NSEL], const unsigned short* Ald,
                                      int strideUsh, const unsigned short* __restrict__ Bg,
                                      int lane, int tile0){
  const int lc = lane & 15, a4 = lane >> 4;
  const unsigned short* a0 = Ald + lc*strideUsh + a4*8;
  const unsigned short* bl = Bg + (size_t)tile0*512 + lane*8;
  #pragma unroll 2
  for(int kc=0;kc<NKC;kc++){
    bf8 av0 = *(const bf8*)(a0 + kc*32);
    bf8 av1;
    if constexpr(NRT==2) av1 = *(const bf8*)(a0 + 16*strideUsh + kc*32);
    #pragma unroll
    for(int s=0;s<NSEL;s++){
      bf8 bv = *(const bf8*)(bl + (size_t)(kc*NTT + s*8)*512);
      acc[0][s] = mfma16(av0, bv, acc[0][s]);
      if constexpr(NRT==2) acc[1][s] = mfma16(av1, bv, acc[1][s]);
    }
  }
}

// ---------------- prep kernels ----------------
__global__ void init_inv(unsigned short* inv, float* outLoss){
  int i = blockIdx.x*256 + threadIdx.x;
  if(i < NT_*B_) inv[i] = 0xFFFFu;
  if(i == 0) *outLoss = 0.f;
}

__global__ void scatter_inv(unsigned short* inv, const int* __restrict__ obs){
  int i = blockIdx.x*256 + threadIdx.x;
  if(i < NT_*NO_){
    int t = i >> 12;
    int o = i & 4095;
    inv[(size_t)t*B_ + obs[i]] = (unsigned short)o;
  }
}

__global__ void build_blobs(const float* __restrict__ pw1, const float* __restrict__ pw2,
                            const float* __restrict__ xzw, const float* __restrict__ xnw,
                            const float* __restrict__ hzw, const float* __restrict__ hnw,
                            const float* __restrict__ wih, const float* __restrict__ whh,
                            const float* __restrict__ wprep, const float* __restrict__ bprep,
                            unsigned short* __restrict__ blob, float* __restrict__ wjp){
  int sec = blockIdx.y;
  int e = blockIdx.x*256 + threadIdx.x;
  if(sec==7){
    // repack w_prep [d][4][10] + bias_prep [d][10] -> wjp [d][pr][5], row stride 51
    if(e < 32*51){
      int d = e/51, r = e%51, pr = r/5, c = r%5;
      float v = 0.f;
      if(pr < PREP_) v = (c<4) ? wprep[d*40 + c*10 + pr] : bprep[d*10 + pr];
      wjp[e] = v;
    }
    return;
  }
  const float* src=nullptr; int N, ld, off, cnt;
  switch(sec){
    case 0: src=nullptr; N=256; ld=0;   off=OFF_XZXN; cnt=16384;  break; // [xz|xn]
    case 1: src=hzw;  N=128; ld=128; off=OFF_HZ;   cnt=16384;  break;
    case 2: src=hnw;  N=128; ld=128; off=OFF_HN;   cnt=16384;  break;
    case 3: src=pw1;  N=64;  ld=64;  off=OFF_PW1;  cnt=8192;   break;
    case 4: src=pw2;  N=64;  ld=64;  off=OFF_PW2;  cnt=4096;   break;
    case 5: src=wih;  N=384; ld=384; off=OFF_WIH;  cnt=122880; break;
    default:src=whh;  N=384; ld=384; off=OFF_WHH;  cnt=49152;  break;
  }
  if(e >= cnt) return;
  int ntiles = N >> 4;
  int perkc = ntiles << 9;
  int kc = e / perkc, rem = e % perkc;
  int nt = rem >> 9, li = rem & 511;
  int lane = li >> 3, j = li & 7;
  int n = nt*16 + (lane & 15);
  int k = kc*32 + ((lane>>4)&3)*4 + (j&3) + ((j>>2)<<4);
  float v;
  if(sec==0) v = (n<128) ? xzw[(size_t)k*128+n] : xnw[(size_t)k*128 + (n-128)];
  else       v = src[(size_t)k*ld + n];
  blob[off + e] = f2bf(v);
}

// ---------------- fused persistent kernel ----------------
// 256 blocks x 512 threads (8 waves = 2 waves/SIMD); 32 rows/block.
// R14 vs R13: gin remapped to (1 d x 2 rows) per thread -> coeff LDS reads
// halve (100->50/thread/t, ~27us of LDS-pipe issue was the largest single
// line-item); gin writes packed via v_cvt_pk_bf16_f32 (20 b16 -> 10 b32).
__global__ __launch_bounds__(512,2) void fused(
    const float* __restrict__ X, const float* __restrict__ M,
    const float* __restrict__ cov,
    const float* __restrict__ cm_w1, const float* __restrict__ cm_b1,
    const float* __restrict__ cm_w2, const float* __restrict__ cm_b2,
    const float* __restrict__ p_b1, const float* __restrict__ p_b2,
    const float* __restrict__ xz_b, const float* __restrict__ xn_b,
    const float* __restrict__ b_ih, const float* __restrict__ b_hh,
    const unsigned short* __restrict__ blob, const float* __restrict__ wjp,
    const unsigned short* __restrict__ inv,
    float* __restrict__ outH, float* __restrict__ outP, float* __restrict__ outLoss)
{
  __shared__ __align__(16) unsigned short wlds[WL_TOT];  // 88KB resident weights
  __shared__ __align__(16) unsigned short hb[32*STRH];   // bf16 h (swizzled)
  __shared__ __align__(16) unsigned short pb[32*STRP];   // bf16 p
  __shared__ __align__(16) unsigned short un[32*STRG];   // union: qb / zh / gin
  __shared__ __align__(16) float pf32[32*PFSTR];         // fp32 p
  __shared__ float sb[SB_TOT];
  __shared__ float sbJ[32*51];                           // packed prep coeffs
  __shared__ int obsO[32];
  __shared__ float lred[8];

  const int tid  = threadIdx.x;
  const int lane = tid & 63;
  const int w    = tid >> 6;           // wave 0..7
  const int lc   = lane & 15;
  const int a4   = lane >> 4;          // 0..3
  const int base = blockIdx.x * 32;
  float lsum = 0.f;

  // ---- stage fp32 constants + resident weights ----
  for(int i=tid;i<128;i+=512){ sb[SB_XZ+i]=xz_b[i]; sb[SB_XN+i]=xn_b[i];
                               sb[SB_BIN+i]=b_ih[256+i]; sb[SB_BHN+i]=b_hh[256+i]; }
  for(int i=tid;i<64;i+=512){ sb[SB_P1+i]=p_b1[i]; sb[SB_P2+i]=p_b2[i]; }
  for(int i=tid;i<256;i+=512) sb[SB_BRZ+i]=b_ih[i]+b_hh[i];
  for(int i=tid;i<32*51;i+=512) sbJ[i]=wjp[i];
  for(int i=tid*8;i<32768;i+=4096) *(uint4*)(wlds+i)      = *(const uint4*)(blob+i);        // XZXN|HZ
  for(int i=tid*8;i<12288;i+=4096) *(uint4*)(wlds+32768+i)= *(const uint4*)(blob+49152+i);  // PW1|PW2

  // ---- init h = tanh(relu(cov@cm_w1+b1)@cm_w2+b2) (one-time scalar path) ----
  {
    float* c1f = pf32;                  // [32][36] scratch
    float* hInitF = (float*)un;         // [32][132] scratch
    int row = tid>>4, q = tid&15;
    float a[2];
    #pragma unroll
    for(int j=0;j<2;j++) a[j]=cm_b1[q*2+j];
    #pragma unroll
    for(int k=0;k<CS_;k++){
      float cv = cov[(size_t)(base+row)*CS_+k];
      #pragma unroll
      for(int j=0;j<2;j++) a[j] += cv*cm_w1[k*CH_+q*2+j];
    }
    #pragma unroll
    for(int j=0;j<2;j++) c1f[row*36+q*2+j] = fmaxf(a[j],0.f);
    __syncthreads();
    float acc2[8];
    #pragma unroll
    for(int j=0;j<8;j++) acc2[j]=cm_b2[q*8+j];
    for(int k=0;k<CH_;k++){
      float cv = c1f[row*36+k];
      #pragma unroll
      for(int j=0;j<8;j++) acc2[j] += cv*cm_w2[k*H_+q*8+j];
    }
    #pragma unroll
    for(int j=0;j<8;j++) hInitF[row*132+q*8+j] = tanhf_(acc2[j]);
    __syncthreads();
  }

  f4 hFr[2];        // h cols [16w,16w+16), rows rt*16+a4*4+g
  f4 pFr;           // p rows prt*16+a4*4+g, col pct*16+lc
  const int prt = w & 1, pct = w >> 1;
  {
    float* hInitF = (float*)un;
    #pragma unroll
    for(int rt=0;rt<2;rt++)
      #pragma unroll
      for(int g=0;g<4;g++)
        hFr[rt][g] = hInitF[(rt*16+a4*4+g)*132 + w*16+lc];
    __syncthreads();                    // reads done before un reuse / hb write
    #pragma unroll
    for(int rt=0;rt<2;rt++)
      #pragma unroll
      for(int g=0;g<4;g++)
        hb[(rt*16+a4*4+g)*STRH + permk(w*16+lc)] = f2bf(hFr[rt][g]);
    __syncthreads();
  }

  // ---- p_model: wave w -> rows [16*prt), cols [16*pct); B from LDS ----
  auto pmodel = [&](){
    f4 acc[1][1];
    { float bv = sb[SB_P1 + pct*16+lc]; f4 t={bv,bv,bv,bv}; acc[0][0]=t; }
    gemmW<4,1,4,1>(acc, hb + prt*16*STRH, STRH, wlds+WL_PW1, lane, pct);
    #pragma unroll
    for(int g=0;g<4;g++)
      un[(prt*16+a4*4+g)*STRP + permk(pct*16+lc)] = f2bf(fmaxf(acc[0][0][g],0.f));
    __syncthreads();
    { float bv = sb[SB_P2 + pct*16+lc]; f4 t={bv,bv,bv,bv}; acc[0][0]=t; }
    gemmW<2,1,4,1>(acc, un + prt*16*STRP, STRP, wlds+WL_PW2, lane, pct);
    pFr = acc[0][0];
    #pragma unroll
    for(int g=0;g<4;g++){
      int row = prt*16+a4*4+g, col = pct*16+lc;
      float v = acc[0][0][g];
      pb[row*STRP + permk(col)] = f2bf(v);
      pf32[row*PFSTR + col] = v;
    }
    __syncthreads();
  };

  // ---- euler: h += DT*(1-z)*(n-h); XZXN+HZ from LDS; HN prefetched to regs ----
  auto euler = [&](){
    // T14 issue-early: HN B-fragments (L2) in flight across phase 1 + barrier
    bf8 hnB[4];
    #pragma unroll
    for(int kc=0;kc<4;kc++)
      hnB[kc] = *(const bf8*)(blob + OFF_HN + (size_t)(kc*8+w)*512 + lane*8);
    f4 ax[2][2];   // [rt][0]=xz part, [rt][1]=xn part (merged 256-wide blob)
    #pragma unroll
    for(int rt=0;rt<2;rt++){
      float bz = sb[SB_XZ + w*16+lc], bn = sb[SB_XN + w*16+lc];
      f4 tz={bz,bz,bz,bz}, tn={bn,bn,bn,bn};
      ax[rt][0]=tz; ax[rt][1]=tn;
    }
    gemmW<2,2,16,2>(ax, pb, STRP, wlds+WL_XZXN, lane, w);
    f4 ah[2][1]; { f4 z4={0.f,0.f,0.f,0.f}; ah[0][0]=z4; ah[1][0]=z4; }
    gemmW<4,1,8,2>(ah, hb, STRH, wlds+WL_HZ, lane, w);
    f4 zr[2];
    #pragma unroll
    for(int rt=0;rt<2;rt++)
      #pragma unroll
      for(int g=0;g<4;g++){
        float z = sigmoidf_(ax[rt][0][g] + ah[rt][0][g]);
        zr[rt][g]=z;
        un[(rt*16+a4*4+g)*STRH + permk(w*16+lc)] = f2bf(z*hFr[rt][g]);   // zh
      }
    __syncthreads();
    // ah2 = zh @ HN with the prefetched B fragments
    f4 ah2[2]; { f4 z4={0.f,0.f,0.f,0.f}; ah2[0]=z4; ah2[1]=z4; }
    {
      const unsigned short* a0 = un + lc*STRH + a4*8;
      #pragma unroll
      for(int kc=0;kc<4;kc++){
        bf8 av0 = *(const bf8*)(a0 + kc*32);
        bf8 av1 = *(const bf8*)(a0 + 16*STRH + kc*32);
        ah2[0] = mfma16(av0, hnB[kc], ah2[0]);
        ah2[1] = mfma16(av1, hnB[kc], ah2[1]);
      }
    }
    #pragma unroll
    for(int rt=0;rt<2;rt++)
      #pragma unroll
      for(int g=0;g<4;g++){
        float nn = tanhf_(ax[rt][1][g] + ah2[rt][g]);
        float ho = hFr[rt][g];
        float hv = ho + DT_*(1.f-zr[rt][g])*(nn-ho);
        hFr[rt][g]=hv;
        hb[(rt*16+a4*4+g)*STRH + permk(w*16+lc)] = f2bf(hv);
      }
    __syncthreads();
  };

  // ---- Bayesian jump: gin remapped (1 d x 2 rows); merged 3-gate GEMMs ----
  auto jump = [&](int o0, int o1, float x0, float m0, float x1, float m1){
    { // gin + loss: thread -> (d = tid&31, rows {2rp, 2rp+1})
      int rp = tid>>5, d = tid&31;
      int row0 = rp*2, row1 = rp*2+1;
      if(d==0){ obsO[row0]=o0; obsO[row1]=o1; }
      float mean0 = pf32[row0*PFSTR + d], lv0 = pf32[row0*PFSTR + D_ + d];
      float mean1 = pf32[row1*PFSTR + d], lv1 = pf32[row1*PFSTR + D_ + d];
      float er0 = (x0-mean0)*__expf(-0.5f*lv0);
      float er1 = (x1-mean1)*__expf(-0.5f*lv1);
      lsum += 0.5f*((er0*er0 + lv0 + TWO_LOGC)*m0 + (er1*er1 + lv1 + TWO_LOGC)*m1);
      const float* wj = sbJ + d*51;
      unsigned short* g0 = un + row0*STRG;
      unsigned short* g1 = un + row1*STRG;
      #pragma unroll
      for(int pr=0;pr<PREP_;pr+=2){
        const float* ca = wj + pr*5;
        const float* cb = ca + 5;
        float sa0 = fmaxf(x0*ca[0] + mean0*ca[1] + lv0*ca[2] + er0*ca[3] + ca[4], 0.f)*m0;
        float sb0 = fmaxf(x0*cb[0] + mean0*cb[1] + lv0*cb[2] + er0*cb[3] + cb[4], 0.f)*m0;
        float sa1 = fmaxf(x1*ca[0] + mean1*ca[1] + lv1*ca[2] + er1*ca[3] + ca[4], 0.f)*m1;
        float sb1 = fmaxf(x1*cb[0] + mean1*cb[1] + lv1*cb[2] + er1*cb[3] + cb[4], 0.f)*m1;
        int pos = permk(d*PREP_ + pr);     // even, pair-adjacent (k&3 in {0,2})
        *(unsigned int*)(g0 + pos) = cvtpk(sa0, sb0);
        *(unsigned int*)(g1 + pos) = cvtpk(sa1, sb1);
      }
    }
    __syncthreads();
    // gi = gin @ [wih_r|wih_z|wih_n] (+biases); gh = h @ [whh_r|whh_z|whh_n]
    f4 gi[2][3];
    #pragma unroll
    for(int rt=0;rt<2;rt++){
      float br = sb[SB_BRZ + w*16+lc], bz = sb[SB_BRZ+128 + w*16+lc], bn = sb[SB_BIN + w*16+lc];
      f4 tr={br,br,br,br}, tz={bz,bz,bz,bz}, tn={bn,bn,bn,bn};
      gi[rt][0]=tr; gi[rt][1]=tz; gi[rt][2]=tn;
    }
    gemmW<10,3,24,2>(gi, un, STRG, blob+OFF_WIH, lane, w);
    f4 gh[2][3];
    #pragma unroll
    for(int rt=0;rt<2;rt++){
      float bhn = sb[SB_BHN + w*16+lc];
      f4 z4={0.f,0.f,0.f,0.f}, tn={bhn,bhn,bhn,bhn};
      gh[rt][0]=z4; gh[rt][1]=z4; gh[rt][2]=tn;
    }
    gemmW<4,3,24,2>(gh, hb, STRH, blob+OFF_WHH, lane, w);
    __syncthreads();   // all waves done reading hb/un before conditional hb writes
    #pragma unroll
    for(int rt=0;rt<2;rt++)
      #pragma unroll
      for(int g=0;g<4;g++){
        int row = rt*16+a4*4+g;
        float r = sigmoidf_(gi[rt][0][g] + gh[rt][0][g]);
        float z = sigmoidf_(gi[rt][1][g] + gh[rt][1][g]);
        float nn = tanhf_(gi[rt][2][g] + r*gh[rt][2][g]);
        float hv = (1.f-z)*nn + z*hFr[rt][g];
        if(obsO[row]>=0){
          hFr[rt][g]=hv;
          hb[row*STRH + permk(w*16+lc)] = f2bf(hv);
        }
      }
    __syncthreads();
  };

  // ---- sequence ----
  pmodel();
  for(int t=0;t<NT_;t++){
    // prefetch this t's jump gathers (consumed ~2 phases later).
    // mapping matches gin: thread -> (d = tid&31, rows {2rp, 2rp+1})
    int rp = tid>>5, d = tid&31;
    unsigned short iv0 = inv[(size_t)t*B_ + base + rp*2];
    unsigned short iv1 = inv[(size_t)t*B_ + base + rp*2 + 1];
    int o0 = (iv0==0xFFFFu)? -1 : (int)iv0;
    int o1 = (iv1==0xFFFFu)? -1 : (int)iv1;
    float x0=0.f,m0=0.f,x1=0.f,m1=0.f;
    if(o0>=0){
      x0 = X[((size_t)t*NO_+o0)*D_ + d];
      m0 = M[((size_t)t*NO_+o0)*D_ + d];
    }
    if(o1>=0){
      x1 = X[((size_t)t*NO_+o1)*D_ + d];
      m1 = M[((size_t)t*NO_+o1)*D_ + d];
    }
    euler();
    pmodel();
    jump(o0, o1, x0, m0, x1, m1);
    pmodel();
  }
  for(int it=0;it<NPOST_;it++){
    euler();
    pmodel();
  }

  // ---- outputs ----
  #pragma unroll
  for(int rt=0;rt<2;rt++)
    #pragma unroll
    for(int g=0;g<4;g++)
      outH[(size_t)(base + rt*16+a4*4+g)*H_ + w*16+lc] = hFr[rt][g];
  #pragma unroll
  for(int g=0;g<4;g++)
    outP[(size_t)(base + prt*16+a4*4+g)*(2*D_) + pct*16+lc] = pFr[g];

  #pragma unroll
  for(int off=32;off>0;off>>=1) lsum += __shfl_down(lsum, off);
  if(lane==0) lred[w]=lsum;
  __syncthreads();
  if(tid==0){
    float s = 0.f;
    #pragma unroll
    for(int i=0;i<8;i++) s += lred[i];
    atomicAdd(outLoss, s);
  }
}

// ---------------- launcher ----------------
extern "C" void kernel_launch(void* const* d_in, const int* in_sizes, int n_in,
                              void* d_out, int out_size, void* d_ws, size_t ws_size,
                              hipStream_t stream){
  const float* X      = (const float*)d_in[0];
  const float* M      = (const float*)d_in[1];
  const int*   obs    = (const int*)  d_in[2];
  const float* cov    = (const float*)d_in[3];
  const float* cm_w1  = (const float*)d_in[4];
  const float* cm_b1  = (const float*)d_in[5];
  const float* cm_w2  = (const float*)d_in[6];
  const float* cm_b2  = (const float*)d_in[7];
  const float* p_w1   = (const float*)d_in[8];
  const float* p_b1   = (const float*)d_in[9];
  const float* p_w2   = (const float*)d_in[10];
  const float* p_b2   = (const float*)d_in[11];
  const float* xz_w   = (const float*)d_in[12];
  const float* xz_b   = (const float*)d_in[13];
  const float* hz_w   = (const float*)d_in[14];
  const float* xn_w   = (const float*)d_in[15];
  const float* xn_b   = (const float*)d_in[16];
  const float* hn_w   = (const float*)d_in[17];
  const float* w_ih   = (const float*)d_in[18];
  const float* w_hh   = (const float*)d_in[19];
  const float* b_ih   = (const float*)d_in[20];
  const float* b_hh   = (const float*)d_in[21];
  const float* w_prep = (const float*)d_in[22];
  const float* bprep  = (const float*)d_in[23];

  unsigned short* blob = (unsigned short*)d_ws;
  unsigned short* inv  = (unsigned short*)((char*)d_ws + INV_BYTE_OFF);
  float*          wjp  = (float*)((char*)d_ws + WJP_BYTE_OFF);
  float* outH = (float*)d_out;
  float* outP = outH + (size_t)B_*H_;
  float* outLoss = outP + (size_t)B_*2*D_;

  init_inv   <<<dim3((NT_*B_+255)/256), dim3(256), 0, stream>>>(inv, outLoss);
  scatter_inv<<<dim3((NT_*NO_+255)/256), dim3(256), 0, stream>>>(inv, obs);
  build_blobs<<<dim3(480,8), dim3(256), 0, stream>>>(p_w1,p_w2,xz_w,xn_w,hz_w,hn_w,w_ih,w_hh,
                                                     w_prep,bprep, blob, wjp);
  fused      <<<dim3(B_/32), dim3(512), 0, stream>>>(
      X, M, cov, cm_w1, cm_b1, cm_w2, cm_b2, p_b1, p_b2, xz_b, xn_b,
      b_ih, b_hh, blob, wjp, inv, outH, outP, outLoss);
}

// Round 15
// 187.359 us; speedup vs baseline: 2.2953x; 1.0110x over previous
//
#include <hip/hip_runtime.h>

// ---------------- problem constants ----------------
#define B_     8192
#define D_     32
#define H_     128
#define PH_    64
#define PREP_  10
#define CS_    8
#define CH_    32
#define NT_    16
#define NO_    4096
#define NPOST_ 4
#define DT_    0.1f
#define TWO_LOGC 1.8378770664093453f   // 2*log(sqrt(2*pi))

// ---------------- bf16 fragment-blob offsets (ushort elements) ----------------
// blob layout for a KxN weight: element ((kc*ntiles+nt)*64+lane)*8+j holds
// W[kc*32 + 4*((lane>>4)&3) + (j&3) + 16*(j>>2)][nt*16 + (lane&15)]
// FXZXN = PW2 @ [xz_w | xn_w] (64x256) -- PW2 folded into the euler GEMM so
// euler consumes q (=relu(h@PW1+b1)) directly; WIH = w_ih (320x384), WHH (128x384).
#define OFF_XZXN 0        // FXZXN 64x256 -> 16384
#define OFF_HZ   16384    // 128x128  -> 16384
#define OFF_HN   32768    // 128x128  -> 16384
#define OFF_PW1  49152    // 128x64   -> 8192
#define OFF_PW2  57344    // 64x64    -> 4096
#define OFF_WIH  61440    // 320x384  -> 122880
#define OFF_WHH  184320   // 128x384  -> 49152
#define BLOB_ELEMS 233472
#define INV_BYTE_OFF ((size_t)BLOB_ELEMS*2)
#define WJP_BYTE_OFF (INV_BYTE_OFF + 262144)   // float[32*51 + 256]: prep coeffs + folded euler bias

// LDS-resident weight copies (ushort offsets inside wlds)
#define WL_XZXN 0
#define WL_HZ   16384
#define WL_PW1  32768
#define WL_PW2  40960
#define WL_TOT  45056      // 88 KB

// activation LDS strides (ushorts): stride_dw % 32 == 4 -> worst 2-way (free)
#define STRH 136
#define STRP 72
#define STRG 328
#define PFSTR 67          // fp32 p stride (floats)

// shared fp32 constant table offsets (floats)
#define SB_XZ    0
#define SB_XN    128
#define SB_P1    256
#define SB_P2    320
#define SB_BRZ   384      // b_ih+b_hh for r (0..127) and z (128..255)
#define SB_BIN   640      // b_ih n-chunk
#define SB_BHN   768      // b_hh n-chunk
#define SB_TOT   896

typedef float f4  __attribute__((ext_vector_type(4)));
typedef short bf8 __attribute__((ext_vector_type(8)));

__device__ __forceinline__ f4 mfma16(bf8 a, bf8 b, f4 c){
  return __builtin_amdgcn_mfma_f32_16x16x32_bf16(a,b,c,0,0,0);
}
__device__ __forceinline__ unsigned short f2bf(float f){
  unsigned int u = __builtin_bit_cast(unsigned int, f);
  u = (u + 0x7FFFu + ((u>>16)&1u)) >> 16;
  return (unsigned short)u;
}
// pack 2 floats -> 2 bf16 (RNE) in one op
__device__ __forceinline__ unsigned int cvtpk(float lo, float hi){
  unsigned int r;
  asm("v_cvt_pk_bf16_f32 %0, %1, %2" : "=v"(r) : "v"(lo), "v"(hi));
  return r;
}
__device__ __forceinline__ float sigmoidf_(float x){ return 1.f/(1.f+__expf(-x)); }
// fast tanh: exact formula, 5 ops, saturates correctly.
__device__ __forceinline__ float tanhf_(float x){
  float e = __expf(2.f*x);
  return 1.f - 2.f/(e+1.f);
}
// column k -> ushort position inside a swizzled activation row (fragment order)
__device__ __forceinline__ int permk(int k){
  return ((k>>5)<<5) | (((k>>2)&3)<<3) | (((k>>4)&1)<<2) | (k&3);
}

// Wave-sliced GEMM: rows = NRT*16, wave owns col tiles {tile0 + s*8 : s<NSEL}
// of an NTT-tile-wide fragment blob. A from swizzled LDS (1 ds_read_b128 per
// row-tile per kc), B streamed from L2 blob OR LDS-resident copy (same layout).
// unroll 2 caps the in-flight load window (anti-spill; R2/R3/R9 lesson).
template<int NKC,int NSEL,int NTT,int NRT>
__device__ __forceinline__ void gemmW(f4 (&acc)[NRT][NSEL], const unsigned short* Ald,
                                      int strideUsh, const unsigned short* __restrict__ Bg,
                                      int lane, int tile0){
  const int lc = lane & 15, a4 = lane >> 4;
  const unsigned short* a0 = Ald + lc*strideUsh + a4*8;
  const unsigned short* bl = Bg + (size_t)tile0*512 + lane*8;
  #pragma unroll 2
  for(int kc=0;kc<NKC;kc++){
    bf8 av0 = *(const bf8*)(a0 + kc*32);
    bf8 av1;
    if constexpr(NRT==2) av1 = *(const bf8*)(a0 + 16*strideUsh + kc*32);
    #pragma unroll
    for(int s=0;s<NSEL;s++){
      bf8 bv = *(const bf8*)(bl + (size_t)(kc*NTT + s*8)*512);
      acc[0][s] = mfma16(av0, bv, acc[0][s]);
      if constexpr(NRT==2) acc[1][s] = mfma16(av1, bv, acc[1][s]);
    }
  }
}

// ---------------- prep kernels ----------------
__global__ void init_inv(unsigned short* inv, float* outLoss){
  int i = blockIdx.x*256 + threadIdx.x;
  if(i < NT_*B_) inv[i] = 0xFFFFu;
  if(i == 0) *outLoss = 0.f;
}

__global__ void scatter_inv(unsigned short* inv, const int* __restrict__ obs){
  int i = blockIdx.x*256 + threadIdx.x;
  if(i < NT_*NO_){
    int t = i >> 12;
    int o = i & 4095;
    inv[(size_t)t*B_ + obs[i]] = (unsigned short)o;
  }
}

__global__ void build_blobs(const float* __restrict__ pw1, const float* __restrict__ pw2,
                            const float* __restrict__ xzw, const float* __restrict__ xnw,
                            const float* __restrict__ hzw, const float* __restrict__ hnw,
                            const float* __restrict__ wih, const float* __restrict__ whh,
                            const float* __restrict__ wprep, const float* __restrict__ bprep,
                            const float* __restrict__ pb2, const float* __restrict__ xzb,
                            const float* __restrict__ xnb,
                            unsigned short* __restrict__ blob, float* __restrict__ wjp){
  int sec = blockIdx.y;
  int e = blockIdx.x*256 + threadIdx.x;
  if(sec==7){
    // repack w_prep [d][4][10] + bias_prep [d][10] -> wjp [d][pr][5], row stride 51
    if(e < 32*51){
      int d = e/51, r = e%51, pr = r/5, c = r%5;
      float v = 0.f;
      if(pr < PREP_) v = (c<4) ? wprep[d*40 + c*10 + pr] : bprep[d*10 + pr];
      wjp[e] = v;
    } else if(e < 32*51 + 256){
      // folded euler bias: fb[n] = b2 @ XZXN[:,n] + [xz_b|xn_b][n]
      int n = e - 32*51;
      float acc = (n<128)? xzb[n] : xnb[n-128];
      for(int m=0;m<2*D_;m++){
        float xz = (n<128)? xzw[(size_t)m*H_+n] : xnw[(size_t)m*H_+(n-128)];
        acc += pb2[m]*xz;
      }
      wjp[e] = acc;
    }
    return;
  }
  const float* src=nullptr; int N, ld, off, cnt;
  switch(sec){
    case 0: src=nullptr; N=256; ld=0;   off=OFF_XZXN; cnt=16384;  break; // FXZXN = pw2 @ [xz|xn]
    case 1: src=hzw;  N=128; ld=128; off=OFF_HZ;   cnt=16384;  break;
    case 2: src=hnw;  N=128; ld=128; off=OFF_HN;   cnt=16384;  break;
    case 3: src=pw1;  N=64;  ld=64;  off=OFF_PW1;  cnt=8192;   break;
    case 4: src=pw2;  N=64;  ld=64;  off=OFF_PW2;  cnt=4096;   break;
    case 5: src=wih;  N=384; ld=384; off=OFF_WIH;  cnt=122880; break;
    default:src=whh;  N=384; ld=384; off=OFF_WHH;  cnt=49152;  break;
  }
  if(e >= cnt) return;
  int ntiles = N >> 4;
  int perkc = ntiles << 9;
  int kc = e / perkc, rem = e % perkc;
  int nt = rem >> 9, li = rem & 511;
  int lane = li >> 3, j = li & 7;
  int n = nt*16 + (lane & 15);
  int k = kc*32 + ((lane>>4)&3)*4 + (j&3) + ((j>>2)<<4);
  float v;
  if(sec==0){
    // FXZXN[k][n] = sum_m pw2[k][m] * XZXN[m][n], k in [0,64)
    float acc = 0.f;
    #pragma unroll 4
    for(int m=0;m<2*D_;m++){
      float xz = (n<128)? xzw[(size_t)m*H_+n] : xnw[(size_t)m*H_+(n-128)];
      acc += pw2[(size_t)k*(2*D_)+m]*xz;
    }
    v = acc;
  }
  else v = src[(size_t)k*ld + n];
  blob[off + e] = f2bf(v);
}

// ---------------- fused persistent kernel ----------------
// 256 blocks x 512 threads (8 waves = 2 waves/SIMD); 32 rows/block.
// R15 vs R14: PW2 folded into the euler GEMM (FXZXN = PW2@XZXN, bias fb =
// b2@XZXN + [xz_b|xn_b]) -> euler consumes q directly; p_model splits into
// Q-phase (1 GEMM, always) and P-phase (pf32 only, before jumps + final).
// Saves 1 GEMM phase + 1 barrier per t, 4 PW2 phases in post-loop, and the
// pb buffer entirely.
__global__ __launch_bounds__(512,2) void fused(
    const float* __restrict__ X, const float* __restrict__ M,
    const float* __restrict__ cov,
    const float* __restrict__ cm_w1, const float* __restrict__ cm_b1,
    const float* __restrict__ cm_w2, const float* __restrict__ cm_b2,
    const float* __restrict__ p_b1, const float* __restrict__ p_b2,
    const float* __restrict__ b_ih, const float* __restrict__ b_hh,
    const unsigned short* __restrict__ blob, const float* __restrict__ wjp,
    const unsigned short* __restrict__ inv,
    float* __restrict__ outH, float* __restrict__ outP, float* __restrict__ outLoss)
{
  __shared__ __align__(16) unsigned short wlds[WL_TOT];  // 88KB resident weights
  __shared__ __align__(16) unsigned short hb[32*STRH];   // bf16 h (swizzled)
  __shared__ __align__(16) unsigned short qb[32*STRP];   // bf16 q (swizzled)
  __shared__ __align__(16) unsigned short un[32*STRG];   // union: zh / gin
  __shared__ __align__(16) float pf32[32*PFSTR];         // fp32 p (jump + output)
  __shared__ float sb[SB_TOT];
  __shared__ float sbJ[32*51];                           // packed prep coeffs
  __shared__ int obsO[32];
  __shared__ float lred[8];

  const int tid  = threadIdx.x;
  const int lane = tid & 63;
  const int w    = tid >> 6;           // wave 0..7
  const int lc   = lane & 15;
  const int a4   = lane >> 4;          // 0..3
  const int base = blockIdx.x * 32;
  float lsum = 0.f;

  // ---- stage fp32 constants + resident weights ----
  const float* fb = wjp + 32*51;
  for(int i=tid;i<128;i+=512){ sb[SB_XZ+i]=fb[i]; sb[SB_XN+i]=fb[128+i];
                               sb[SB_BIN+i]=b_ih[256+i]; sb[SB_BHN+i]=b_hh[256+i]; }
  for(int i=tid;i<64;i+=512){ sb[SB_P1+i]=p_b1[i]; sb[SB_P2+i]=p_b2[i]; }
  for(int i=tid;i<256;i+=512) sb[SB_BRZ+i]=b_ih[i]+b_hh[i];
  for(int i=tid;i<32*51;i+=512) sbJ[i]=wjp[i];
  for(int i=tid*8;i<32768;i+=4096) *(uint4*)(wlds+i)      = *(const uint4*)(blob+i);        // FXZXN|HZ
  for(int i=tid*8;i<12288;i+=4096) *(uint4*)(wlds+32768+i)= *(const uint4*)(blob+49152+i);  // PW1|PW2

  // ---- init h = tanh(relu(cov@cm_w1+b1)@cm_w2+b2) (one-time scalar path) ----
  {
    float* c1f = pf32;                  // [32][36] scratch
    float* hInitF = (float*)un;         // [32][132] scratch
    int row = tid>>4, q = tid&15;
    float a[2];
    #pragma unroll
    for(int j=0;j<2;j++) a[j]=cm_b1[q*2+j];
    #pragma unroll
    for(int k=0;k<CS_;k++){
      float cv = cov[(size_t)(base+row)*CS_+k];
      #pragma unroll
      for(int j=0;j<2;j++) a[j] += cv*cm_w1[k*CH_+q*2+j];
    }
    #pragma unroll
    for(int j=0;j<2;j++) c1f[row*36+q*2+j] = fmaxf(a[j],0.f);
    __syncthreads();
    float acc2[8];
    #pragma unroll
    for(int j=0;j<8;j++) acc2[j]=cm_b2[q*8+j];
    for(int k=0;k<CH_;k++){
      float cv = c1f[row*36+k];
      #pragma unroll
      for(int j=0;j<8;j++) acc2[j] += cv*cm_w2[k*H_+q*8+j];
    }
    #pragma unroll
    for(int j=0;j<8;j++) hInitF[row*132+q*8+j] = tanhf_(acc2[j]);
    __syncthreads();
  }

  f4 hFr[2];        // h cols [16w,16w+16), rows rt*16+a4*4+g
  f4 pFr;           // final p, rows prt*16+a4*4+g, col pct*16+lc
  const int prt = w & 1, pct = w >> 1;
  {
    float* hInitF = (float*)un;
    #pragma unroll
    for(int rt=0;rt<2;rt++)
      #pragma unroll
      for(int g=0;g<4;g++)
        hFr[rt][g] = hInitF[(rt*16+a4*4+g)*132 + w*16+lc];
    __syncthreads();                    // reads done before un reuse / hb write
    #pragma unroll
    for(int rt=0;rt<2;rt++)
      #pragma unroll
      for(int g=0;g<4;g++)
        hb[(rt*16+a4*4+g)*STRH + permk(w*16+lc)] = f2bf(hFr[rt][g]);
    __syncthreads();
  }

  // ---- Q-phase: q = relu(h@PW1+b1) -> qb; wave w -> rows 16*prt, cols 16*pct ----
  auto qphase = [&](){
    f4 acc[1][1];
    { float bv = sb[SB_P1 + pct*16+lc]; f4 t={bv,bv,bv,bv}; acc[0][0]=t; }
    gemmW<4,1,4,1>(acc, hb + prt*16*STRH, STRH, wlds+WL_PW1, lane, pct);
    #pragma unroll
    for(int g=0;g<4;g++)
      qb[(prt*16+a4*4+g)*STRP + permk(pct*16+lc)] = f2bf(fmaxf(acc[0][0][g],0.f));
    __syncthreads();
  };

  // ---- P-phase: p = q@PW2+b2 -> pf32 (and pFr when final) ----
  auto pphase = [&](bool fin){
    f4 acc[1][1];
    { float bv = sb[SB_P2 + pct*16+lc]; f4 t={bv,bv,bv,bv}; acc[0][0]=t; }
    gemmW<2,1,4,1>(acc, qb + prt*16*STRP, STRP, wlds+WL_PW2, lane, pct);
    if(fin) pFr = acc[0][0];
    #pragma unroll
    for(int g=0;g<4;g++)
      pf32[(prt*16+a4*4+g)*PFSTR + pct*16+lc] = acc[0][0][g];
    __syncthreads();
  };

  // ---- euler: h += DT*(1-z)*(n-h); q@FXZXN + h@HZ from LDS; HN prefetched ----
  auto euler = [&](){
    // T14 issue-early: HN B-fragments (L2) in flight across phase 1 + barrier
    bf8 hnB[4];
    #pragma unroll
    for(int kc=0;kc<4;kc++)
      hnB[kc] = *(const bf8*)(blob + OFF_HN + (size_t)(kc*8+w)*512 + lane*8);
    f4 ax[2][2];   // [rt][0]=xz part, [rt][1]=xn part (merged 256-wide blob)
    #pragma unroll
    for(int rt=0;rt<2;rt++){
      float bz = sb[SB_XZ + w*16+lc], bn = sb[SB_XN + w*16+lc];
      f4 tz={bz,bz,bz,bz}, tn={bn,bn,bn,bn};
      ax[rt][0]=tz; ax[rt][1]=tn;
    }
    gemmW<2,2,16,2>(ax, qb, STRP, wlds+WL_XZXN, lane, w);
    f4 ah[2][1]; { f4 z4={0.f,0.f,0.f,0.f}; ah[0][0]=z4; ah[1][0]=z4; }
    gemmW<4,1,8,2>(ah, hb, STRH, wlds+WL_HZ, lane, w);
    f4 zr[2];
    #pragma unroll
    for(int rt=0;rt<2;rt++)
      #pragma unroll
      for(int g=0;g<4;g++){
        float z = sigmoidf_(ax[rt][0][g] + ah[rt][0][g]);
        zr[rt][g]=z;
        un[(rt*16+a4*4+g)*STRH + permk(w*16+lc)] = f2bf(z*hFr[rt][g]);   // zh
      }
    __syncthreads();
    // ah2 = zh @ HN with the prefetched B fragments
    f4 ah2[2]; { f4 z4={0.f,0.f,0.f,0.f}; ah2[0]=z4; ah2[1]=z4; }
    {
      const unsigned short* a0 = un + lc*STRH + a4*8;
      #pragma unroll
      for(int kc=0;kc<4;kc++){
        bf8 av0 = *(const bf8*)(a0 + kc*32);
        bf8 av1 = *(const bf8*)(a0 + 16*STRH + kc*32);
        ah2[0] = mfma16(av0, hnB[kc], ah2[0]);
        ah2[1] = mfma16(av1, hnB[kc], ah2[1]);
      }
    }
    #pragma unroll
    for(int rt=0;rt<2;rt++)
      #pragma unroll
      for(int g=0;g<4;g++){
        float nn = tanhf_(ax[rt][1][g] + ah2[rt][g]);
        float ho = hFr[rt][g];
        float hv = ho + DT_*(1.f-zr[rt][g])*(nn-ho);
        hFr[rt][g]=hv;
        hb[(rt*16+a4*4+g)*STRH + permk(w*16+lc)] = f2bf(hv);
      }
    __syncthreads();
  };

  // ---- Bayesian jump: gin (1 d x 2 rows per thread); merged 3-gate GEMMs ----
  auto jump = [&](int o0, int o1, float x0, float m0, float x1, float m1){
    { // gin + loss: thread -> (d = tid&31, rows {2rp, 2rp+1})
      int rp = tid>>5, d = tid&31;
      int row0 = rp*2, row1 = rp*2+1;
      if(d==0){ obsO[row0]=o0; obsO[row1]=o1; }
      float mean0 = pf32[row0*PFSTR + d], lv0 = pf32[row0*PFSTR + D_ + d];
      float mean1 = pf32[row1*PFSTR + d], lv1 = pf32[row1*PFSTR + D_ + d];
      float er0 = (x0-mean0)*__expf(-0.5f*lv0);
      float er1 = (x1-mean1)*__expf(-0.5f*lv1);
      lsum += 0.5f*((er0*er0 + lv0 + TWO_LOGC)*m0 + (er1*er1 + lv1 + TWO_LOGC)*m1);
      const float* wj = sbJ + d*51;
      unsigned short* g0 = un + row0*STRG;
      unsigned short* g1 = un + row1*STRG;
      #pragma unroll
      for(int pr=0;pr<PREP_;pr+=2){
        const float* ca = wj + pr*5;
        const float* cb = ca + 5;
        float sa0 = fmaxf(x0*ca[0] + mean0*ca[1] + lv0*ca[2] + er0*ca[3] + ca[4], 0.f)*m0;
        float sb0 = fmaxf(x0*cb[0] + mean0*cb[1] + lv0*cb[2] + er0*cb[3] + cb[4], 0.f)*m0;
        float sa1 = fmaxf(x1*ca[0] + mean1*ca[1] + lv1*ca[2] + er1*ca[3] + ca[4], 0.f)*m1;
        float sb1 = fmaxf(x1*cb[0] + mean1*cb[1] + lv1*cb[2] + er1*cb[3] + cb[4], 0.f)*m1;
        int pos = permk(d*PREP_ + pr);     // even, pair-adjacent (k&3 in {0,2})
        *(unsigned int*)(g0 + pos) = cvtpk(sa0, sb0);
        *(unsigned int*)(g1 + pos) = cvtpk(sa1, sb1);
      }
    }
    __syncthreads();
    // gi = gin @ [wih_r|wih_z|wih_n] (+biases); gh = h @ [whh_r|whh_z|whh_n]
    f4 gi[2][3];
    #pragma unroll
    for(int rt=0;rt<2;rt++){
      float br = sb[SB_BRZ + w*16+lc], bz = sb[SB_BRZ+128 + w*16+lc], bn = sb[SB_BIN + w*16+lc];
      f4 tr={br,br,br,br}, tz={bz,bz,bz,bz}, tn={bn,bn,bn,bn};
      gi[rt][0]=tr; gi[rt][1]=tz; gi[rt][2]=tn;
    }
    gemmW<10,3,24,2>(gi, un, STRG, blob+OFF_WIH, lane, w);
    f4 gh[2][3];
    #pragma unroll
    for(int rt=0;rt<2;rt++){
      float bhn = sb[SB_BHN + w*16+lc];
      f4 z4={0.f,0.f,0.f,0.f}, tn={bhn,bhn,bhn,bhn};
      gh[rt][0]=z4; gh[rt][1]=z4; gh[rt][2]=tn;
    }
    gemmW<4,3,24,2>(gh, hb, STRH, blob+OFF_WHH, lane, w);
    __syncthreads();   // all waves done reading hb/un before conditional hb writes
    #pragma unroll
    for(int rt=0;rt<2;rt++)
      #pragma unroll
      for(int g=0;g<4;g++){
        int row = rt*16+a4*4+g;
        float r = sigmoidf_(gi[rt][0][g] + gh[rt][0][g]);
        float z = sigmoidf_(gi[rt][1][g] + gh[rt][1][g]);
        float nn = tanhf_(gi[rt][2][g] + r*gh[rt][2][g]);
        float hv = (1.f-z)*nn + z*hFr[rt][g];
        if(obsO[row]>=0){
          hFr[rt][g]=hv;
          hb[row*STRH + permk(w*16+lc)] = f2bf(hv);
        }
      }
    __syncthreads();
  };

  // ---- sequence ----
  qphase();                       // q for first euler
  for(int t=0;t<NT_;t++){
    // prefetch this t's jump gathers (consumed ~3 phases later).
    // mapping matches gin: thread -> (d = tid&31, rows {2rp, 2rp+1})
    int rp = tid>>5, d = tid&31;
    unsigned short iv0 = inv[(size_t)t*B_ + base + rp*2];
    unsigned short iv1 = inv[(size_t)t*B_ + base + rp*2 + 1];
    int o0 = (iv0==0xFFFFu)? -1 : (int)iv0;
    int o1 = (iv1==0xFFFFu)? -1 : (int)iv1;
    float x0=0.f,m0=0.f,x1=0.f,m1=0.f;
    if(o0>=0){
      x0 = X[((size_t)t*NO_+o0)*D_ + d];
      m0 = M[((size_t)t*NO_+o0)*D_ + d];
    }
    if(o1>=0){
      x1 = X[((size_t)t*NO_+o1)*D_ + d];
      m1 = M[((size_t)t*NO_+o1)*D_ + d];
    }
    euler();
    qphase();                     // q at post-euler h (feeds P and, later, next euler)
    pphase(false);                // p for the jump (pf32 only)
    jump(o0, o1, x0, m0, x1, m1);
    qphase();                     // q at post-jump h
  }
  for(int it=0;it<NPOST_;it++){
    euler();
    qphase();
  }
  pphase(true);                   // final p for output

  // ---- outputs ----
  #pragma unroll
  for(int rt=0;rt<2;rt++)
    #pragma unroll
    for(int g=0;g<4;g++)
      outH[(size_t)(base + rt*16+a4*4+g)*H_ + w*16+lc] = hFr[rt][g];
  #pragma unroll
  for(int g=0;g<4;g++)
    outP[(size_t)(base + prt*16+a4*4+g)*(2*D_) + pct*16+lc] = pFr[g];

  #pragma unroll
  for(int off=32;off>0;off>>=1) lsum += __shfl_down(lsum, off);
  if(lane==0) lred[w]=lsum;
  __syncthreads();
  if(tid==0){
    float s = 0.f;
    #pragma unroll
    for(int i=0;i<8;i++) s += lred[i];
    atomicAdd(outLoss, s);
  }
}

// ---------------- launcher ----------------
extern "C" void kernel_launch(void* const* d_in, const int* in_sizes, int n_in,
                              void* d_out, int out_size, void* d_ws, size_t ws_size,
                              hipStream_t stream){
  const float* X      = (const float*)d_in[0];
  const float* M      = (const float*)d_in[1];
  const int*   obs    = (const int*)  d_in[2];
  const float* cov    = (const float*)d_in[3];
  const float* cm_w1  = (const float*)d_in[4];
  const float* cm_b1  = (const float*)d_in[5];
  const float* cm_w2  = (const float*)d_in[6];
  const float* cm_b2  = (const float*)d_in[7];
  const float* p_w1   = (const float*)d_in[8];
  const float* p_b1   = (const float*)d_in[9];
  const float* p_w2   = (const float*)d_in[10];
  const float* p_b2   = (const float*)d_in[11];
  const float* xz_w   = (const float*)d_in[12];
  const float* xz_b   = (const float*)d_in[13];
  const float* hz_w   = (const float*)d_in[14];
  const float* xn_w   = (const float*)d_in[15];
  const float* xn_b   = (const float*)d_in[16];
  const float* hn_w   = (const float*)d_in[17];
  const float* w_ih   = (const float*)d_in[18];
  const float* w_hh   = (const float*)d_in[19];
  const float* b_ih   = (const float*)d_in[20];
  const float* b_hh   = (const float*)d_in[21];
  const float* w_prep = (const float*)d_in[22];
  const float* bprep  = (const float*)d_in[23];

  unsigned short* blob = (unsigned short*)d_ws;
  unsigned short* inv  = (unsigned short*)((char*)d_ws + INV_BYTE_OFF);
  float*          wjp  = (float*)((char*)d_ws + WJP_BYTE_OFF);
  float* outH = (float*)d_out;
  float* outP = outH + (size_t)B_*H_;
  float* outLoss = outP + (size_t)B_*2*D_;

  init_inv   <<<dim3((NT_*B_+255)/256), dim3(256), 0, stream>>>(inv, outLoss);
  scatter_inv<<<dim3((NT_*NO_+255)/256), dim3(256), 0, stream>>>(inv, obs);
  build_blobs<<<dim3(480,8), dim3(256), 0, stream>>>(p_w1,p_w2,xz_w,xn_w,hz_w,hn_w,w_ih,w_hh,
                                                     w_prep,bprep,p_b2,xz_b,xn_b, blob, wjp);
  fused      <<<dim3(B_/32), dim3(512), 0, stream>>>(
      X, M, cov, cm_w1, cm_b1, cm_w2, cm_b2, p_b1, p_b2,
      b_ih, b_hh, blob, wjp, inv, outH, outP, outLoss);
}

// Round 16
// 176.841 us; speedup vs baseline: 2.4318x; 1.0595x over previous
//
#include <hip/hip_runtime.h>

// ---------------- problem constants ----------------
#define B_     8192
#define D_     32
#define H_     128
#define PH_    64
#define PREP_  10
#define CS_    8
#define CH_    32
#define NT_    16
#define NO_    4096
#define NPOST_ 4
#define DT_    0.1f
#define TWO_LOGC 1.8378770664093453f   // 2*log(sqrt(2*pi))

// ---------------- bf16 fragment-blob offsets (ushort elements) ----------------
// blob layout for a KxN weight: element ((kc*ntiles+nt)*64+lane)*8+j holds
// W[kc*32 + 4*((lane>>4)&3) + (j&3) + 16*(j>>2)][nt*16 + (lane&15)]
// FXZXN = PW2 @ [xz_w | xn_w] (64x256) -- PW2 folded into the euler GEMM so
// euler consumes q (=relu(h@PW1+b1)) directly; WIH = w_ih (320x384), WHH (128x384).
#define OFF_XZXN 0        // FXZXN 64x256 -> 16384
#define OFF_HZ   16384    // 128x128  -> 16384
#define OFF_HN   32768    // 128x128  -> 16384
#define OFF_PW1  49152    // 128x64   -> 8192
#define OFF_PW2  57344    // 64x64    -> 4096
#define OFF_WIH  61440    // 320x384  -> 122880
#define OFF_WHH  184320   // 128x384  -> 49152
#define BLOB_ELEMS 233472
#define INV_BYTE_OFF ((size_t)BLOB_ELEMS*2)
#define WJP_BYTE_OFF (INV_BYTE_OFF + 262144)   // float[32*51 + 256]: prep coeffs + folded euler bias

// LDS-resident weight copies (ushort offsets inside wlds)
#define WL_XZXN 0
#define WL_HZ   16384
#define WL_PW1  32768
#define WL_PW2  40960
#define WL_TOT  45056      // 88 KB

// activation LDS strides (ushorts): stride_dw % 32 == 4 -> worst 2-way (free)
#define STRH 136
#define STRP 72
#define STRG 328
#define PFSTR 67          // fp32 p stride (floats)

// shared fp32 constant table offsets (floats)
#define SB_XZ    0
#define SB_XN    128
#define SB_P1    256
#define SB_P2    320
#define SB_BRZ   384      // b_ih+b_hh for r (0..127) and z (128..255)
#define SB_BIN   640      // b_ih n-chunk
#define SB_BHN   768      // b_hh n-chunk
#define SB_TOT   896

typedef float f4  __attribute__((ext_vector_type(4)));
typedef short bf8 __attribute__((ext_vector_type(8)));

__device__ __forceinline__ f4 mfma16(bf8 a, bf8 b, f4 c){
  return __builtin_amdgcn_mfma_f32_16x16x32_bf16(a,b,c,0,0,0);
}
__device__ __forceinline__ unsigned short f2bf(float f){
  unsigned int u = __builtin_bit_cast(unsigned int, f);
  u = (u + 0x7FFFu + ((u>>16)&1u)) >> 16;
  return (unsigned short)u;
}
// pack 2 floats -> 2 bf16 (RNE) in one op
__device__ __forceinline__ unsigned int cvtpk(float lo, float hi){
  unsigned int r;
  asm("v_cvt_pk_bf16_f32 %0, %1, %2" : "=v"(r) : "v"(lo), "v"(hi));
  return r;
}
__device__ __forceinline__ float sigmoidf_(float x){ return 1.f/(1.f+__expf(-x)); }
// fast tanh: exact formula, 5 ops, saturates correctly.
__device__ __forceinline__ float tanhf_(float x){
  float e = __expf(2.f*x);
  return 1.f - 2.f/(e+1.f);
}
// column k -> ushort position inside a swizzled activation row (fragment order)
__device__ __forceinline__ int permk(int k){
  return ((k>>5)<<5) | (((k>>2)&3)<<3) | (((k>>4)&1)<<2) | (k&3);
}

// Wave-sliced GEMM: rows = NRT*16, wave owns col tiles {tile0 + s*8 : s<NSEL}
// of an NTT-tile-wide fragment blob. A from swizzled LDS (1 ds_read_b128 per
// row-tile per kc), B streamed from L2 blob OR LDS-resident copy (same layout).
// unroll 2 caps the in-flight load window (anti-spill; R2/R3/R9 lesson).
template<int NKC,int NSEL,int NTT,int NRT>
__device__ __forceinline__ void gemmW(f4 (&acc)[NRT][NSEL], const unsigned short* Ald,
                                      int strideUsh, const unsigned short* __restrict__ Bg,
                                      int lane, int tile0){
  const int lc = lane & 15, a4 = lane >> 4;
  const unsigned short* a0 = Ald + lc*strideUsh + a4*8;
  const unsigned short* bl = Bg + (size_t)tile0*512 + lane*8;
  #pragma unroll 2
  for(int kc=0;kc<NKC;kc++){
    bf8 av0 = *(const bf8*)(a0 + kc*32);
    bf8 av1;
    if constexpr(NRT==2) av1 = *(const bf8*)(a0 + 16*strideUsh + kc*32);
    #pragma unroll
    for(int s=0;s<NSEL;s++){
      bf8 bv = *(const bf8*)(bl + (size_t)(kc*NTT + s*8)*512);
      acc[0][s] = mfma16(av0, bv, acc[0][s]);
      if constexpr(NRT==2) acc[1][s] = mfma16(av1, bv, acc[1][s]);
    }
  }
}

// ---------------- prep kernels ----------------
__global__ void init_inv(unsigned short* inv, float* outLoss){
  int i = blockIdx.x*256 + threadIdx.x;
  if(i < NT_*B_) inv[i] = 0xFFFFu;
  if(i == 0) *outLoss = 0.f;
}

__global__ void scatter_inv(unsigned short* inv, const int* __restrict__ obs){
  int i = blockIdx.x*256 + threadIdx.x;
  if(i < NT_*NO_){
    int t = i >> 12;
    int o = i & 4095;
    inv[(size_t)t*B_ + obs[i]] = (unsigned short)o;
  }
}

__global__ void build_blobs(const float* __restrict__ pw1, const float* __restrict__ pw2,
                            const float* __restrict__ xzw, const float* __restrict__ xnw,
                            const float* __restrict__ hzw, const float* __restrict__ hnw,
                            const float* __restrict__ wih, const float* __restrict__ whh,
                            const float* __restrict__ wprep, const float* __restrict__ bprep,
                            const float* __restrict__ pb2, const float* __restrict__ xzb,
                            const float* __restrict__ xnb,
                            unsigned short* __restrict__ blob, float* __restrict__ wjp){
  int sec = blockIdx.y;
  int e = blockIdx.x*256 + threadIdx.x;
  if(sec==7){
    // repack w_prep [d][4][10] + bias_prep [d][10] -> wjp [d][pr][5], row stride 51
    if(e < 32*51){
      int d = e/51, r = e%51, pr = r/5, c = r%5;
      float v = 0.f;
      if(pr < PREP_) v = (c<4) ? wprep[d*40 + c*10 + pr] : bprep[d*10 + pr];
      wjp[e] = v;
    } else if(e < 32*51 + 256){
      // folded euler bias: fb[n] = b2 @ XZXN[:,n] + [xz_b|xn_b][n]
      int n = e - 32*51;
      float acc = (n<128)? xzb[n] : xnb[n-128];
      for(int m=0;m<2*D_;m++){
        float xz = (n<128)? xzw[(size_t)m*H_+n] : xnw[(size_t)m*H_+(n-128)];
        acc += pb2[m]*xz;
      }
      wjp[e] = acc;
    }
    return;
  }
  const float* src=nullptr; int N, ld, off, cnt;
  switch(sec){
    case 0: src=nullptr; N=256; ld=0;   off=OFF_XZXN; cnt=16384;  break; // FXZXN = pw2 @ [xz|xn]
    case 1: src=hzw;  N=128; ld=128; off=OFF_HZ;   cnt=16384;  break;
    case 2: src=hnw;  N=128; ld=128; off=OFF_HN;   cnt=16384;  break;
    case 3: src=pw1;  N=64;  ld=64;  off=OFF_PW1;  cnt=8192;   break;
    case 4: src=pw2;  N=64;  ld=64;  off=OFF_PW2;  cnt=4096;   break;
    case 5: src=wih;  N=384; ld=384; off=OFF_WIH;  cnt=122880; break;
    default:src=whh;  N=384; ld=384; off=OFF_WHH;  cnt=49152;  break;
  }
  if(e >= cnt) return;
  int ntiles = N >> 4;
  int perkc = ntiles << 9;
  int kc = e / perkc, rem = e % perkc;
  int nt = rem >> 9, li = rem & 511;
  int lane = li >> 3, j = li & 7;
  int n = nt*16 + (lane & 15);
  int k = kc*32 + ((lane>>4)&3)*4 + (j&3) + ((j>>2)<<4);
  float v;
  if(sec==0){
    // FXZXN[k][n] = sum_m pw2[k][m] * XZXN[m][n], k in [0,64)
    float acc = 0.f;
    #pragma unroll 4
    for(int m=0;m<2*D_;m++){
      float xz = (n<128)? xzw[(size_t)m*H_+n] : xnw[(size_t)m*H_+(n-128)];
      acc += pw2[(size_t)k*(2*D_)+m]*xz;
    }
    v = acc;
  }
  else v = src[(size_t)k*ld + n];
  blob[off + e] = f2bf(v);
}

// ---------------- fused persistent kernel ----------------
// 256 blocks x 512 threads (8 waves = 2 waves/SIMD); 32 rows/block.
// R16 vs R15: jump restructured -- gh GEMM (h@WHH, no gin dependency) moved
// BEFORE the gin phase so its L2 loads overlap gin's VALU; gi's kc=0 B-batch
// preloaded (T14); post-GEMM barrier deleted (nothing reads hb between the
// mid and trailing barriers). Jump barriers 3->2; gh off the critical path.
__global__ __launch_bounds__(512,2) void fused(
    const float* __restrict__ X, const float* __restrict__ M,
    const float* __restrict__ cov,
    const float* __restrict__ cm_w1, const float* __restrict__ cm_b1,
    const float* __restrict__ cm_w2, const float* __restrict__ cm_b2,
    const float* __restrict__ p_b1, const float* __restrict__ p_b2,
    const float* __restrict__ b_ih, const float* __restrict__ b_hh,
    const unsigned short* __restrict__ blob, const float* __restrict__ wjp,
    const unsigned short* __restrict__ inv,
    float* __restrict__ outH, float* __restrict__ outP, float* __restrict__ outLoss)
{
  __shared__ __align__(16) unsigned short wlds[WL_TOT];  // 88KB resident weights
  __shared__ __align__(16) unsigned short hb[32*STRH];   // bf16 h (swizzled)
  __shared__ __align__(16) unsigned short qb[32*STRP];   // bf16 q (swizzled)
  __shared__ __align__(16) unsigned short un[32*STRG];   // union: zh / gin
  __shared__ __align__(16) float pf32[32*PFSTR];         // fp32 p (jump + output)
  __shared__ float sb[SB_TOT];
  __shared__ float sbJ[32*51];                           // packed prep coeffs
  __shared__ int obsO[32];
  __shared__ float lred[8];

  const int tid  = threadIdx.x;
  const int lane = tid & 63;
  const int w    = tid >> 6;           // wave 0..7
  const int lc   = lane & 15;
  const int a4   = lane >> 4;          // 0..3
  const int base = blockIdx.x * 32;
  float lsum = 0.f;

  // ---- stage fp32 constants + resident weights ----
  const float* fb = wjp + 32*51;
  for(int i=tid;i<128;i+=512){ sb[SB_XZ+i]=fb[i]; sb[SB_XN+i]=fb[128+i];
                               sb[SB_BIN+i]=b_ih[256+i]; sb[SB_BHN+i]=b_hh[256+i]; }
  for(int i=tid;i<64;i+=512){ sb[SB_P1+i]=p_b1[i]; sb[SB_P2+i]=p_b2[i]; }
  for(int i=tid;i<256;i+=512) sb[SB_BRZ+i]=b_ih[i]+b_hh[i];
  for(int i=tid;i<32*51;i+=512) sbJ[i]=wjp[i];
  for(int i=tid*8;i<32768;i+=4096) *(uint4*)(wlds+i)      = *(const uint4*)(blob+i);        // FXZXN|HZ
  for(int i=tid*8;i<12288;i+=4096) *(uint4*)(wlds+32768+i)= *(const uint4*)(blob+49152+i);  // PW1|PW2

  // ---- init h = tanh(relu(cov@cm_w1+b1)@cm_w2+b2) (one-time scalar path) ----
  {
    float* c1f = pf32;                  // [32][36] scratch
    float* hInitF = (float*)un;         // [32][132] scratch
    int row = tid>>4, q = tid&15;
    float a[2];
    #pragma unroll
    for(int j=0;j<2;j++) a[j]=cm_b1[q*2+j];
    #pragma unroll
    for(int k=0;k<CS_;k++){
      float cv = cov[(size_t)(base+row)*CS_+k];
      #pragma unroll
      for(int j=0;j<2;j++) a[j] += cv*cm_w1[k*CH_+q*2+j];
    }
    #pragma unroll
    for(int j=0;j<2;j++) c1f[row*36+q*2+j] = fmaxf(a[j],0.f);
    __syncthreads();
    float acc2[8];
    #pragma unroll
    for(int j=0;j<8;j++) acc2[j]=cm_b2[q*8+j];
    for(int k=0;k<CH_;k++){
      float cv = c1f[row*36+k];
      #pragma unroll
      for(int j=0;j<8;j++) acc2[j] += cv*cm_w2[k*H_+q*8+j];
    }
    #pragma unroll
    for(int j=0;j<8;j++) hInitF[row*132+q*8+j] = tanhf_(acc2[j]);
    __syncthreads();
  }

  f4 hFr[2];        // h cols [16w,16w+16), rows rt*16+a4*4+g
  f4 pFr;           // final p, rows prt*16+a4*4+g, col pct*16+lc
  const int prt = w & 1, pct = w >> 1;
  {
    float* hInitF = (float*)un;
    #pragma unroll
    for(int rt=0;rt<2;rt++)
      #pragma unroll
      for(int g=0;g<4;g++)
        hFr[rt][g] = hInitF[(rt*16+a4*4+g)*132 + w*16+lc];
    __syncthreads();                    // reads done before un reuse / hb write
    #pragma unroll
    for(int rt=0;rt<2;rt++)
      #pragma unroll
      for(int g=0;g<4;g++)
        hb[(rt*16+a4*4+g)*STRH + permk(w*16+lc)] = f2bf(hFr[rt][g]);
    __syncthreads();
  }

  // ---- Q-phase: q = relu(h@PW1+b1) -> qb; wave w -> rows 16*prt, cols 16*pct ----
  auto qphase = [&](){
    f4 acc[1][1];
    { float bv = sb[SB_P1 + pct*16+lc]; f4 t={bv,bv,bv,bv}; acc[0][0]=t; }
    gemmW<4,1,4,1>(acc, hb + prt*16*STRH, STRH, wlds+WL_PW1, lane, pct);
    #pragma unroll
    for(int g=0;g<4;g++)
      qb[(prt*16+a4*4+g)*STRP + permk(pct*16+lc)] = f2bf(fmaxf(acc[0][0][g],0.f));
    __syncthreads();
  };

  // ---- P-phase: p = q@PW2+b2 -> pf32 (and pFr when final) ----
  auto pphase = [&](bool fin){
    f4 acc[1][1];
    { float bv = sb[SB_P2 + pct*16+lc]; f4 t={bv,bv,bv,bv}; acc[0][0]=t; }
    gemmW<2,1,4,1>(acc, qb + prt*16*STRP, STRP, wlds+WL_PW2, lane, pct);
    if(fin) pFr = acc[0][0];
    #pragma unroll
    for(int g=0;g<4;g++)
      pf32[(prt*16+a4*4+g)*PFSTR + pct*16+lc] = acc[0][0][g];
    __syncthreads();
  };

  // ---- euler: h += DT*(1-z)*(n-h); q@FXZXN + h@HZ from LDS; HN prefetched ----
  auto euler = [&](){
    // T14 issue-early: HN B-fragments (L2) in flight across phase 1 + barrier
    bf8 hnB[4];
    #pragma unroll
    for(int kc=0;kc<4;kc++)
      hnB[kc] = *(const bf8*)(blob + OFF_HN + (size_t)(kc*8+w)*512 + lane*8);
    f4 ax[2][2];   // [rt][0]=xz part, [rt][1]=xn part (merged 256-wide blob)
    #pragma unroll
    for(int rt=0;rt<2;rt++){
      float bz = sb[SB_XZ + w*16+lc], bn = sb[SB_XN + w*16+lc];
      f4 tz={bz,bz,bz,bz}, tn={bn,bn,bn,bn};
      ax[rt][0]=tz; ax[rt][1]=tn;
    }
    gemmW<2,2,16,2>(ax, qb, STRP, wlds+WL_XZXN, lane, w);
    f4 ah[2][1]; { f4 z4={0.f,0.f,0.f,0.f}; ah[0][0]=z4; ah[1][0]=z4; }
    gemmW<4,1,8,2>(ah, hb, STRH, wlds+WL_HZ, lane, w);
    f4 zr[2];
    #pragma unroll
    for(int rt=0;rt<2;rt++)
      #pragma unroll
      for(int g=0;g<4;g++){
        float z = sigmoidf_(ax[rt][0][g] + ah[rt][0][g]);
        zr[rt][g]=z;
        un[(rt*16+a4*4+g)*STRH + permk(w*16+lc)] = f2bf(z*hFr[rt][g]);   // zh
      }
    __syncthreads();
    // ah2 = zh @ HN with the prefetched B fragments
    f4 ah2[2]; { f4 z4={0.f,0.f,0.f,0.f}; ah2[0]=z4; ah2[1]=z4; }
    {
      const unsigned short* a0 = un + lc*STRH + a4*8;
      #pragma unroll
      for(int kc=0;kc<4;kc++){
        bf8 av0 = *(const bf8*)(a0 + kc*32);
        bf8 av1 = *(const bf8*)(a0 + 16*STRH + kc*32);
        ah2[0] = mfma16(av0, hnB[kc], ah2[0]);
        ah2[1] = mfma16(av1, hnB[kc], ah2[1]);
      }
    }
    #pragma unroll
    for(int rt=0;rt<2;rt++)
      #pragma unroll
      for(int g=0;g<4;g++){
        float nn = tanhf_(ax[rt][1][g] + ah2[rt][g]);
        float ho = hFr[rt][g];
        float hv = ho + DT_*(1.f-zr[rt][g])*(nn-ho);
        hFr[rt][g]=hv;
        hb[(rt*16+a4*4+g)*STRH + permk(w*16+lc)] = f2bf(hv);
      }
    __syncthreads();
  };

  // ---- Bayesian jump (R16 restructure):
  //  1. preload gi kc=0 B-fragments (T14)
  //  2. gh GEMM first (reads hb -- stable since euler's barrier; no gin dep)
  //  3. gin VALU (overlaps gh/pre L2 traffic)  4. barrier
  //  5. gi GEMM (peeled kc=0 + kc=1..9)        6. epilogue (no extra barrier:
  //     hb readers are all pre-mid-barrier)     7. trailing barrier
  auto jump = [&](int o0, int o1, float x0, float m0, float x1, float m1){
    bf8 pre[3];
    #pragma unroll
    for(int s=0;s<3;s++)
      pre[s] = *(const bf8*)(blob + OFF_WIH + (size_t)(w + s*8)*512 + lane*8);
    // gh = h @ [whh_r|whh_z|whh_n] (+ b_hh n-chunk)
    f4 gh[2][3];
    #pragma unroll
    for(int rt=0;rt<2;rt++){
      float bhn = sb[SB_BHN + w*16+lc];
      f4 z4={0.f,0.f,0.f,0.f}, tn={bhn,bhn,bhn,bhn};
      gh[rt][0]=z4; gh[rt][1]=z4; gh[rt][2]=tn;
    }
    gemmW<4,3,24,2>(gh, hb, STRH, blob+OFF_WHH, lane, w);
    { // gin + loss: thread -> (d = tid&31, rows {2rp, 2rp+1})
      int rp = tid>>5, d = tid&31;
      int row0 = rp*2, row1 = rp*2+1;
      if(d==0){ obsO[row0]=o0; obsO[row1]=o1; }
      float mean0 = pf32[row0*PFSTR + d], lv0 = pf32[row0*PFSTR + D_ + d];
      float mean1 = pf32[row1*PFSTR + d], lv1 = pf32[row1*PFSTR + D_ + d];
      float er0 = (x0-mean0)*__expf(-0.5f*lv0);
      float er1 = (x1-mean1)*__expf(-0.5f*lv1);
      lsum += 0.5f*((er0*er0 + lv0 + TWO_LOGC)*m0 + (er1*er1 + lv1 + TWO_LOGC)*m1);
      const float* wj = sbJ + d*51;
      unsigned short* g0 = un + row0*STRG;
      unsigned short* g1 = un + row1*STRG;
      #pragma unroll
      for(int pr=0;pr<PREP_;pr+=2){
        const float* ca = wj + pr*5;
        const float* cb = ca + 5;
        float sa0 = fmaxf(x0*ca[0] + mean0*ca[1] + lv0*ca[2] + er0*ca[3] + ca[4], 0.f)*m0;
        float sb0 = fmaxf(x0*cb[0] + mean0*cb[1] + lv0*cb[2] + er0*cb[3] + cb[4], 0.f)*m0;
        float sa1 = fmaxf(x1*ca[0] + mean1*ca[1] + lv1*ca[2] + er1*ca[3] + ca[4], 0.f)*m1;
        float sb1 = fmaxf(x1*cb[0] + mean1*cb[1] + lv1*cb[2] + er1*cb[3] + cb[4], 0.f)*m1;
        int pos = permk(d*PREP_ + pr);     // even, pair-adjacent (k&3 in {0,2})
        *(unsigned int*)(g0 + pos) = cvtpk(sa0, sb0);
        *(unsigned int*)(g1 + pos) = cvtpk(sa1, sb1);
      }
    }
    __syncthreads();
    // gi = gin @ [wih_r|wih_z|wih_n] (+biases); kc=0 peeled with preloaded B
    f4 gi[2][3];
    #pragma unroll
    for(int rt=0;rt<2;rt++){
      float br = sb[SB_BRZ + w*16+lc], bz = sb[SB_BRZ+128 + w*16+lc], bn = sb[SB_BIN + w*16+lc];
      f4 tr={br,br,br,br}, tz={bz,bz,bz,bz}, tn={bn,bn,bn,bn};
      gi[rt][0]=tr; gi[rt][1]=tz; gi[rt][2]=tn;
    }
    {
      const unsigned short* A = un + lc*STRG + a4*8;
      bf8 av0 = *(const bf8*)(A);
      bf8 av1 = *(const bf8*)(A + 16*STRG);
      #pragma unroll
      for(int s=0;s<3;s++){
        gi[0][s] = mfma16(av0, pre[s], gi[0][s]);
        gi[1][s] = mfma16(av1, pre[s], gi[1][s]);
      }
    }
    gemmW<9,3,24,2>(gi, un+32, STRG, blob+OFF_WIH + 24*512, lane, w);
    // epilogue: writes hb; all hb READS happened before the mid barrier.
    #pragma unroll
    for(int rt=0;rt<2;rt++)
      #pragma unroll
      for(int g=0;g<4;g++){
        int row = rt*16+a4*4+g;
        float r = sigmoidf_(gi[rt][0][g] + gh[rt][0][g]);
        float z = sigmoidf_(gi[rt][1][g] + gh[rt][1][g]);
        float nn = tanhf_(gi[rt][2][g] + r*gh[rt][2][g]);
        float hv = (1.f-z)*nn + z*hFr[rt][g];
        if(obsO[row]>=0){
          hFr[rt][g]=hv;
          hb[row*STRH + permk(w*16+lc)] = f2bf(hv);
        }
      }
    __syncthreads();
  };

  // ---- sequence ----
  qphase();                       // q for first euler
  for(int t=0;t<NT_;t++){
    // prefetch this t's jump gathers (consumed ~3 phases later).
    // mapping matches gin: thread -> (d = tid&31, rows {2rp, 2rp+1})
    int rp = tid>>5, d = tid&31;
    unsigned short iv0 = inv[(size_t)t*B_ + base + rp*2];
    unsigned short iv1 = inv[(size_t)t*B_ + base + rp*2 + 1];
    int o0 = (iv0==0xFFFFu)? -1 : (int)iv0;
    int o1 = (iv1==0xFFFFu)? -1 : (int)iv1;
    float x0=0.f,m0=0.f,x1=0.f,m1=0.f;
    if(o0>=0){
      x0 = X[((size_t)t*NO_+o0)*D_ + d];
      m0 = M[((size_t)t*NO_+o0)*D_ + d];
    }
    if(o1>=0){
      x1 = X[((size_t)t*NO_+o1)*D_ + d];
      m1 = M[((size_t)t*NO_+o1)*D_ + d];
    }
    euler();
    qphase();                     // q at post-euler h (feeds P)
    pphase(false);                // p for the jump (pf32 only)
    jump(o0, o1, x0, m0, x1, m1);
    qphase();                     // q at post-jump h (feeds next euler)
  }
  for(int it=0;it<NPOST_;it++){
    euler();
    qphase();
  }
  pphase(true);                   // final p for output

  // ---- outputs ----
  #pragma unroll
  for(int rt=0;rt<2;rt++)
    #pragma unroll
    for(int g=0;g<4;g++)
      outH[(size_t)(base + rt*16+a4*4+g)*H_ + w*16+lc] = hFr[rt][g];
  #pragma unroll
  for(int g=0;g<4;g++)
    outP[(size_t)(base + prt*16+a4*4+g)*(2*D_) + pct*16+lc] = pFr[g];

  #pragma unroll
  for(int off=32;off>0;off>>=1) lsum += __shfl_down(lsum, off);
  if(lane==0) lred[w]=lsum;
  __syncthreads();
  if(tid==0){
    float s = 0.f;
    #pragma unroll
    for(int i=0;i<8;i++) s += lred[i];
    atomicAdd(outLoss, s);
  }
}

// ---------------- launcher ----------------
extern "C" void kernel_launch(void* const* d_in, const int* in_sizes, int n_in,
                              void* d_out, int out_size, void* d_ws, size_t ws_size,
                              hipStream_t stream){
  const float* X      = (const float*)d_in[0];
  const float* M      = (const float*)d_in[1];
  const int*   obs    = (const int*)  d_in[2];
  const float* cov    = (const float*)d_in[3];
  const float* cm_w1  = (const float*)d_in[4];
  const float* cm_b1  = (const float*)d_in[5];
  const float* cm_w2  = (const float*)d_in[6];
  const float* cm_b2  = (const float*)d_in[7];
  const float* p_w1   = (const float*)d_in[8];
  const float* p_b1   = (const float*)d_in[9];
  const float* p_w2   = (const float*)d_in[10];
  const float* p_b2   = (const float*)d_in[11];
  const float* xz_w   = (const float*)d_in[12];
  const float* xz_b   = (const float*)d_in[13];
  const float* hz_w   = (const float*)d_in[14];
  const float* xn_w   = (const float*)d_in[15];
  const float* xn_b   = (const float*)d_in[16];
  const float* hn_w   = (const float*)d_in[17];
  const float* w_ih   = (const float*)d_in[18];
  const float* w_hh   = (const float*)d_in[19];
  const float* b_ih   = (const float*)d_in[20];
  const float* b_hh   = (const float*)d_in[21];
  const float* w_prep = (const float*)d_in[22];
  const float* bprep  = (const float*)d_in[23];

  unsigned short* blob = (unsigned short*)d_ws;
  unsigned short* inv  = (unsigned short*)((char*)d_ws + INV_BYTE_OFF);
  float*          wjp  = (float*)((char*)d_ws + WJP_BYTE_OFF);
  float* outH = (float*)d_out;
  float* outP = outH + (size_t)B_*H_;
  float* outLoss = outP + (size_t)B_*2*D_;

  init_inv   <<<dim3((NT_*B_+255)/256), dim3(256), 0, stream>>>(inv, outLoss);
  scatter_inv<<<dim3((NT_*NO_+255)/256), dim3(256), 0, stream>>>(inv, obs);
  build_blobs<<<dim3(480,8), dim3(256), 0, stream>>>(p_w1,p_w2,xz_w,xn_w,hz_w,hn_w,w_ih,w_hh,
                                                     w_prep,bprep,p_b2,xz_b,xn_b, blob, wjp);
  fused      <<<dim3(B_/32), dim3(512), 0, stream>>>(
      X, M, cov, cm_w1, cm_b1, cm_w2, cm_b2, p_b1, p_b2,
      b_ih, b_hh, blob, wjp, inv, outH, outP, outLoss);
}